// Round 18
// baseline (274.081 us; speedup 1.0000x reference)
//
#include <hip/hip_runtime.h>
#include <hip/hip_bf16.h>
#include <math.h>

#define TT 32
#define NN 2048
#define FF 64

typedef float f32x4 __attribute__((ext_vector_type(4)));
typedef __bf16 bf16x8 __attribute__((ext_vector_type(8)));
typedef unsigned short u16x8 __attribute__((ext_vector_type(8)));

__device__ __forceinline__ unsigned short f2bf(float f) {
    __bf16 h = (__bf16)f;
    return __builtin_bit_cast(unsigned short, h);
}

// ---------------------------------------------------------------------------
// K_S: wide scoring kernel. grid (8, 32) x 256.  (R17-proven)
// ---------------------------------------------------------------------------
__global__ __launch_bounds__(256) void score_kernel(
    const float* __restrict__ X, const float* __restrict__ mask,
    const float* __restrict__ scorer,
    double* __restrict__ scores, unsigned short* __restrict__ Xbf)
{
    const int t = blockIdx.y, tid = threadIdx.x;
    const int n = blockIdx.x * 256 + tid;
    __shared__ float scf[64];
    if (tid < 64) scf[tid] = scorer[tid];
    __syncthreads();

    double nrm = 0.0;
#pragma unroll
    for (int f = 0; f < 64; ++f) nrm += (double)scf[f] * (double)scf[f];
    const double inv = 1.0 / sqrt(nrm);

    const float* xr = X + ((size_t)t * NN + n) * FF;
    unsigned short* xo = Xbf + ((size_t)t * NN + n) * FF;
    double s = 0.0;
#pragma unroll
    for (int f = 0; f < 64; f += 4) {
        float4 v = *(const float4*)(xr + f);
        s += (double)v.x * (double)scf[f]   + (double)v.y * (double)scf[f+1]
           + (double)v.z * (double)scf[f+2] + (double)v.w * (double)scf[f+3];
        ushort4 pk = make_ushort4(f2bf(v.x), f2bf(v.y), f2bf(v.z), f2bf(v.w));
        *(ushort4*)(xo + f) = pk;
    }
    scores[t * NN + n] = s * inv + (double)mask[t * NN + n];
}

// ---------------------------------------------------------------------------
// K_A select v2: 32 blocks x 1024.  Per-wave sorted top-64 extraction
// (R17-proven) -> RANK-MERGE of 16 sorted lists (barrier-free binary
// search; exact: rank<64 implies all counts exact).  No bitonic.
// ---------------------------------------------------------------------------
__global__ __launch_bounds__(1024) void select_kernel(
    const double* __restrict__ scores,
    int* __restrict__ tkidx, float* __restrict__ tkval)
{
    const int t = blockIdx.x, tid = threadIdx.x;
    const int lane = tid & 63, w = tid >> 6;
    __shared__ double sk[1024];
    __shared__ int    si[1024];

    double ls0 = scores[t * NN + tid];
    double ls1 = scores[t * NN + 1024 + tid];

    for (int r = 0; r < 64; ++r) {
        double bv; int bi;
        if (ls0 > ls1 || (ls0 == ls1)) { bv = ls0; bi = (w << 6) + lane; }
        else                           { bv = ls1; bi = 1024 + (w << 6) + lane; }
#pragma unroll
        for (int off = 1; off < 64; off <<= 1) {
            double ov = __shfl_xor(bv, off);
            int    oi = __shfl_xor(bi, off);
            if (ov > bv || (ov == bv && oi < bi)) { bv = ov; bi = oi; }
        }
        if (lane == 0) { sk[(w << 6) + r] = bv; si[(w << 6) + r] = bi; }
        if ((bi & 63) == lane) {
            if (bi < 1024) ls0 = -INFINITY; else ls1 = -INFINITY;
        }
    }
    __syncthreads();

    // rank-merge: candidate c = (sk[tid], si[tid]) at own-wave pos r.
    const double cs = sk[tid];
    const int    ci = si[tid];
    int rank = lane == (tid & 63) ? (tid & 63) : 0;  // r = tid&63
    rank = tid & 63;
#pragma unroll
    for (int w2 = 0; w2 < 16; ++w2) {
        if (w2 == w) continue;
        const double* L = &sk[w2 << 6];
        const int*    I = &si[w2 << 6];
        int lo = 0, hi = 64;
        while (lo < hi) {
            const int mid = (lo + hi) >> 1;
            const double ms = L[mid];
            const bool better = (ms > cs) || (ms == cs && I[mid] < ci);
            if (better) lo = mid + 1; else hi = mid;
        }
        rank += lo;
    }
    if (rank < 64) {
        tkidx[t * 64 + rank] = ci;
        tkval[t * 64 + rank] = tanhf((float)cs);
    }
}

// ---------------------------------------------------------------------------
// K_B qchain v7: 64 blocks x 256.  Phase A (4 waves): z-prefetch + W@z
// precompute (R17-proven).  Phase B: REPLICATED serial recurrence — every
// wave runs it on wave-private LDS q/rr (lane = full row, no shuffles, no
// block barriers; same-wave DS ordering + wave_barrier fences).
// Wave 0 stores Qtr[t][j][f] bf16.
// ---------------------------------------------------------------------------
__global__ __launch_bounds__(256) void qchain_kernel(
    const float* __restrict__ Q0,
    const float* __restrict__ Uu, const float* __restrict__ Ur,
    const float* __restrict__ Uh,
    const float* __restrict__ Wu, const float* __restrict__ Wr,
    const float* __restrict__ Wh,
    const float* __restrict__ bu, const float* __restrict__ br,
    const float* __restrict__ bh,
    const int* __restrict__ tkidx, const float* __restrict__ tkval,
    const float* __restrict__ X, unsigned short* __restrict__ Qtr)
{
    const int j = blockIdx.x, tid = threadIdx.x;
    const int w = tid >> 6, l = tid & 63;

    __shared__ __align__(16) float zsh[TT][64];      // 8 KB
    __shared__ __align__(16) float wzl[3 * TT * 64]; // 24 KB
    __shared__ __align__(16) float qp[4][64];        // wave-private q
    __shared__ __align__(16) float rp[4][64];        // wave-private r

    // ---- phase A1: prefetch z rows (R17 mapping) ----
    {
        const int tt = tid >> 3, p8 = (tid & 7) << 3;
        const int idxt = tkidx[tt * 64 + j];
        const float th = tkval[tt * 64 + j];
        const float* xr = X + ((size_t)tt * NN + idxt) * FF + p8;
        float4 v0 = *(const float4*)(xr);
        float4 v1 = *(const float4*)(xr + 4);
        zsh[tt][p8]     = v0.x * th; zsh[tt][p8 + 1] = v0.y * th;
        zsh[tt][p8 + 2] = v0.z * th; zsh[tt][p8 + 3] = v0.w * th;
        zsh[tt][p8 + 4] = v1.x * th; zsh[tt][p8 + 5] = v1.y * th;
        zsh[tt][p8 + 6] = v1.z * th; zsh[tt][p8 + 7] = v1.w * th;
    }

    // ---- phase A2: W_m @ z_t precompute (R17-proven layout) ----
    {
        const int i = (w << 4) + (l & 15);
        const int fq = l >> 4, fb = fq << 4;
        float wu[16], wr[16], wh[16];
#pragma unroll
        for (int e = 0; e < 16; e += 4) {
            float4 p = *(const float4*)(Wu + i * 64 + fb + e);
            wu[e] = p.x; wu[e+1] = p.y; wu[e+2] = p.z; wu[e+3] = p.w;
            float4 s = *(const float4*)(Wr + i * 64 + fb + e);
            wr[e] = s.x; wr[e+1] = s.y; wr[e+2] = s.z; wr[e+3] = s.w;
            float4 g = *(const float4*)(Wh + i * 64 + fb + e);
            wh[e] = g.x; wh[e+1] = g.y; wh[e+2] = g.z; wh[e+3] = g.w;
        }
        __syncthreads();   // zsh ready
        for (int t = 0; t < TT; ++t) {
            float pu = 0.f, pr = 0.f, ph = 0.f;
#pragma unroll
            for (int e = 0; e < 16; e += 4) {
                f32x4 z = *(const f32x4*)(&zsh[t][fb + e]);
                pu += wu[e]*z[0] + wu[e+1]*z[1] + wu[e+2]*z[2] + wu[e+3]*z[3];
                pr += wr[e]*z[0] + wr[e+1]*z[1] + wr[e+2]*z[2] + wr[e+3]*z[3];
                ph += wh[e]*z[0] + wh[e+1]*z[1] + wh[e+2]*z[2] + wh[e+3]*z[3];
            }
            pu += __shfl_xor(pu, 16); pu += __shfl_xor(pu, 32);
            pr += __shfl_xor(pr, 16); pr += __shfl_xor(pr, 32);
            ph += __shfl_xor(ph, 16); ph += __shfl_xor(ph, 32);
            if (fq == 0) {
                wzl[(0 * TT + t) * 64 + i] = pu;
                wzl[(1 * TT + t) * 64 + i] = pr;
                wzl[(2 * TT + t) * 64 + i] = ph;
            }
        }
    }
    // init wave-private q
    qp[w][l] = Q0[l * 64 + j];
    __syncthreads();   // wzl + qp ready

    // ---- phase B: replicated serial recurrence (lane = row l) ----
    float uu2[64], ur2[64], uh2[64];
#pragma unroll
    for (int f = 0; f < 64; f += 4) {
        float4 a = *(const float4*)(Uu + l * 64 + f);
        uu2[f] = a.x; uu2[f+1] = a.y; uu2[f+2] = a.z; uu2[f+3] = a.w;
        float4 c = *(const float4*)(Ur + l * 64 + f);
        ur2[f] = c.x; ur2[f+1] = c.y; ur2[f+2] = c.z; ur2[f+3] = c.w;
        float4 d = *(const float4*)(Uh + l * 64 + f);
        uh2[f] = d.x; uh2[f+1] = d.y; uh2[f+2] = d.z; uh2[f+3] = d.w;
    }
    const float bu2 = bu[l * 64 + j];
    const float br2 = br[l * 64 + j];
    const float bh2 = bh[l * 64 + j];

    for (int t = 0; t < TT; ++t) {
        const float qi = qp[w][l];
        float su = 0.f, sr = 0.f;
#pragma unroll
        for (int f = 0; f < 64; f += 4) {
            f32x4 qv = *(const f32x4*)(&qp[w][f]);
            su += uu2[f]*qv[0] + uu2[f+1]*qv[1] + uu2[f+2]*qv[2] + uu2[f+3]*qv[3];
            sr += ur2[f]*qv[0] + ur2[f+1]*qv[1] + ur2[f+2]*qv[2] + ur2[f+3]*qv[3];
        }
        const float u_ = 1.f / (1.f + expf(-(su + wzl[(0 * TT + t) * 64 + l] + bu2)));
        const float r_ = 1.f / (1.f + expf(-(sr + wzl[(1 * TT + t) * 64 + l] + br2)));
        rp[w][l] = r_;
        __builtin_amdgcn_wave_barrier();
        float sh = 0.f;
#pragma unroll
        for (int f = 0; f < 64; f += 4) {
            f32x4 qv = *(const f32x4*)(&qp[w][f]);
            f32x4 rv = *(const f32x4*)(&rp[w][f]);
            sh += uh2[f]  *(rv[0]*qv[0]) + uh2[f+1]*(rv[1]*qv[1])
                + uh2[f+2]*(rv[2]*qv[2]) + uh2[f+3]*(rv[3]*qv[3]);
        }
        float hv = sh + wzl[(2 * TT + t) * 64 + l] + bh2;
        hv = hv > 0.f ? hv : 0.f;
        const float qn = (1.f - u_) * qi + u_ * hv;
        __builtin_amdgcn_wave_barrier();
        qp[w][l] = qn;
        if (w == 0) Qtr[(size_t)t * 4096 + j * 64 + l] = f2bf(qn);
        __builtin_amdgcn_wave_barrier();
    }
}

// ---------------------------------------------------------------------------
// K_C y-MFMA (R17-proven): Ytr[t][j][n] = bf16( Qtr[t][j][:] . Xbf[t][n][:] )
// ---------------------------------------------------------------------------
__global__ __launch_bounds__(256) void ymfma_kernel(
    const unsigned short* __restrict__ Xbf, const unsigned short* __restrict__ Qtr,
    unsigned short* __restrict__ Ytr)
{
    __shared__ __align__(16) unsigned char Qb[8192];   // bf16 [64 j][128B]
    const int t = blockIdx.y, tid = threadIdx.x;
    const int n0 = blockIdx.x * 256;
    const int lane = tid & 63, w = tid >> 6;
    const int lr = lane & 15, lq = lane >> 4;

    const unsigned short* Qp = Qtr + (size_t)t * 4096;
#pragma unroll
    for (int q2 = 0; q2 < 2; ++q2) {
        const int j = (w << 4) + (q2 << 3) + (lane >> 3);
        const unsigned short* g = Qp + (size_t)j * 64 + (((lane & 7) ^ (j & 7)) << 3);
        __builtin_amdgcn_global_load_lds(
            (const __attribute__((address_space(1))) void*)g,
            (__attribute__((address_space(3))) void*)
                (&Qb[((w << 4) + (q2 << 3)) << 7]), 16, 0, 0);
    }
    __syncthreads();

    f32x4 acc[4][4];
#pragma unroll
    for (int jt = 0; jt < 4; ++jt)
#pragma unroll
        for (int nt = 0; nt < 4; ++nt) acc[jt][nt] = (f32x4){0.f, 0.f, 0.f, 0.f};

#pragma unroll
    for (int ks = 0; ks < 2; ++ks) {
        bf16x8 af[4], bf[4];
#pragma unroll
        for (int jt = 0; jt < 4; ++jt) {
            const int j = (jt << 4) + lr;
            const int x = ((ks << 2) + lq) ^ (j & 7);
            af[jt] = *(const bf16x8*)(&Qb[(j << 7) + (x << 4)]);
        }
#pragma unroll
        for (int nt = 0; nt < 4; ++nt) {
            const int n = n0 + (w << 6) + (nt << 4) + lr;
            bf[nt] = __builtin_bit_cast(bf16x8,
                *(const uint4*)(Xbf + ((size_t)t * NN + n) * FF + (ks << 5) + (lq << 3)));
        }
#pragma unroll
        for (int jt = 0; jt < 4; ++jt)
#pragma unroll
            for (int nt = 0; nt < 4; ++nt)
                acc[jt][nt] = __builtin_amdgcn_mfma_f32_16x16x32_bf16(
                    af[jt], bf[nt], acc[jt][nt], 0, 0, 0);
    }

#pragma unroll
    for (int jt = 0; jt < 4; ++jt)
#pragma unroll
        for (int nt = 0; nt < 4; ++nt) {
            const int nn = n0 + (w << 6) + (nt << 4) + lr;
#pragma unroll
            for (int rg = 0; rg < 4; ++rg) {
                const int j = (jt << 4) + (lq << 2) + rg;
                Ytr[(size_t)t * FF * NN + (size_t)j * NN + nn] = f2bf(acc[jt][nt][rg]);
            }
        }
}

// ---------------------------------------------------------------------------
// K_D: out[t] = relu(A[t] @ Y[t]).  R10 gemm (measured 112us @ 4.6 TB/s).
// ---------------------------------------------------------------------------
__global__ __launch_bounds__(256, 4) void gemm_kernel(
    const float* __restrict__ A, const unsigned short* __restrict__ Ytr,
    float* __restrict__ out)
{
    __shared__ __align__(16) unsigned char Abuf[16384];  // f32 [64 r][256B]
    __shared__ __align__(16) unsigned char Bbuf[8192];   // bf16 [64 j][128B]
    const int tid = threadIdx.x;
    const int bid = blockIdx.x;
    const int xcd = bid & 7, li = bid >> 3;          // 8 XCDs x 128 blocks
    const int t = (xcd << 2) + (li >> 5);            // 4 timesteps per XCD
    const int m0 = (li & 31) * 64;
    const int lane = tid & 63, w = tid >> 6;
    const int lr = lane & 15, lq = lane >> 4;

    const float* Ap = A + (size_t)t * NN * NN + (size_t)m0 * NN;
    const unsigned short* Yp = Ytr + (size_t)t * FF * NN;

    f32x4 acc[4];
#pragma unroll
    for (int nt = 0; nt < 4; ++nt) acc[nt] = (f32x4){0.f, 0.f, 0.f, 0.f};

    for (int kt = 0; kt < 32; ++kt) {
        const int kk = kt << 6;
#pragma unroll
        for (int q = 0; q < 4; ++q) {
            const int row = (w << 4) + (q << 2) + lq;
            const float* g = Ap + (size_t)row * NN + kk + ((lr ^ (row & 7)) << 2);
            __builtin_amdgcn_global_load_lds(
                (const __attribute__((address_space(1))) void*)g,
                (__attribute__((address_space(3))) void*)
                    (&Abuf[((w << 4) + (q << 2)) << 8]), 16, 0, 0);
        }
#pragma unroll
        for (int q = 0; q < 2; ++q) {
            const int j = (w << 4) + (q << 3) + (lane >> 3);
            const unsigned short* g = Yp + (size_t)j * NN + kk
                                    + (((lane & 7) ^ (j & 7)) << 3);
            __builtin_amdgcn_global_load_lds(
                (const __attribute__((address_space(1))) void*)g,
                (__attribute__((address_space(3))) void*)
                    (&Bbuf[((w << 4) + (q << 3)) << 7]), 16, 0, 0);
        }
        __syncthreads();
#pragma unroll
        for (int ks = 0; ks < 2; ++ks) {
            const int r = (w << 4) + lr;
            const int c0 = ((ks << 3) + (lq << 1)) ^ (lr & 7);
            const int c1 = ((ks << 3) + (lq << 1) + 1) ^ (lr & 7);
            const f32x4 a0 = *(const f32x4*)(&Abuf[(r << 8) + (c0 << 4)]);
            const f32x4 a1 = *(const f32x4*)(&Abuf[(r << 8) + (c1 << 4)]);
            bf16x8 af;
            af[0] = (__bf16)a0[0]; af[1] = (__bf16)a0[1];
            af[2] = (__bf16)a0[2]; af[3] = (__bf16)a0[3];
            af[4] = (__bf16)a1[0]; af[5] = (__bf16)a1[1];
            af[6] = (__bf16)a1[2]; af[7] = (__bf16)a1[3];
#pragma unroll
            for (int nt = 0; nt < 4; ++nt) {
                const int j = (nt << 4) + lr;
                const int x = ((ks << 2) + lq) ^ (j & 7);
                const bf16x8 bf = *(const bf16x8*)(&Bbuf[(j << 7) + (x << 4)]);
                acc[nt] = __builtin_amdgcn_mfma_f32_16x16x32_bf16(
                    af, bf, acc[nt], 0, 0, 0);
            }
        }
        __syncthreads();
    }

#pragma unroll
    for (int nt = 0; nt < 4; ++nt) {
        const int row0 = m0 + (w << 4) + (lq << 2);
        const int col = (nt << 4) + lr;
#pragma unroll
        for (int rg = 0; rg < 4; ++rg) {
            const float v = acc[nt][rg];
            out[((size_t)t * NN + (row0 + rg)) * FF + col] = v > 0.f ? v : 0.f;
        }
    }
}

// ---------------------------------------------------------------------------
extern "C" void kernel_launch(void* const* d_in, const int* in_sizes, int n_in,
                              void* d_out, int out_size, void* d_ws, size_t ws_size,
                              hipStream_t stream) {
    const float* A      = (const float*)d_in[0];
    const float* X      = (const float*)d_in[1];
    const float* mask   = (const float*)d_in[2];
    const float* Q0     = (const float*)d_in[3];
    const float* scorer = (const float*)d_in[4];
    const float* Wu     = (const float*)d_in[5];
    const float* Uu     = (const float*)d_in[6];
    const float* bu     = (const float*)d_in[7];
    const float* Wr     = (const float*)d_in[8];
    const float* Ur     = (const float*)d_in[9];
    const float* br     = (const float*)d_in[10];
    const float* Wh     = (const float*)d_in[11];
    const float* Uh     = (const float*)d_in[12];
    const float* bh     = (const float*)d_in[13];
    float* out = (float*)d_out;

    float* ws = (float*)d_ws;
    double* scores        = (double*)ws;                          // [32][2048] fp64
    int*    tkidx         = (int*)(ws + 131072);                  // [32][64]
    float*  tkval         = ws + 133120;                          // [32][64]
    unsigned short* Qtr   = (unsigned short*)(ws + 135168);       // [32][64][64] bf16
    unsigned short* Xbf   = (unsigned short*)(ws + 200704);       // [32][2048][64] bf16
    unsigned short* Ytr   = (unsigned short*)(ws + 2297856);      // [32][64][2048] bf16

    score_kernel<<<dim3(8, TT), 256, 0, stream>>>(X, mask, scorer, scores, Xbf);
    select_kernel<<<TT, 1024, 0, stream>>>(scores, tkidx, tkval);
    qchain_kernel<<<FF, 256, 0, stream>>>(Q0, Uu, Ur, Uh, Wu, Wr, Wh,
                                          bu, br, bh, tkidx, tkval, X, Qtr);
    ymfma_kernel<<<dim3(8, TT), 256, 0, stream>>>(Xbf, Qtr, Ytr);
    gemm_kernel<<<1024, 256, 0, stream>>>(A, Ytr, out);
}

// Round 19
// 272.739 us; speedup vs baseline: 1.0049x; 1.0049x over previous
//
#include <hip/hip_runtime.h>
#include <hip/hip_bf16.h>
#include <math.h>

#define TT 32
#define NN 2048
#define FF 64

typedef float f32x4 __attribute__((ext_vector_type(4)));
typedef __bf16 bf16x8 __attribute__((ext_vector_type(8)));
typedef unsigned short u16x8 __attribute__((ext_vector_type(8)));

__device__ __forceinline__ unsigned short f2bf(float f) {
    __bf16 h = (__bf16)f;
    return __builtin_bit_cast(unsigned short, h);
}

// ---------------------------------------------------------------------------
// K_A selscore: 32 blocks x 1024.  In-block fp64 scoring (thread -> rows
// tid and 1024+tid) -> per-wave top-64 extraction -> 1024-candidate bitonic
// (both R17-proven verbatim) -> (idx, tanh(val)).
// ---------------------------------------------------------------------------
__global__ __launch_bounds__(1024) void selscore_kernel(
    const float* __restrict__ X, const float* __restrict__ mask,
    const float* __restrict__ scorer,
    int* __restrict__ tkidx, float* __restrict__ tkval)
{
    const int t = blockIdx.x, tid = threadIdx.x;
    const int lane = tid & 63, w = tid >> 6;
    __shared__ float  scf[64];
    __shared__ double sk[1024];
    __shared__ int    si[1024];

    if (tid < 64) scf[tid] = scorer[tid];
    __syncthreads();

    double nrm = 0.0;
#pragma unroll
    for (int f = 0; f < 64; ++f) nrm += (double)scf[f] * (double)scf[f];
    const double inv = 1.0 / sqrt(nrm);

    const float* Xt = X + (size_t)t * NN * FF;
    double ls0, ls1;
    {
        const float* xr0 = Xt + (size_t)tid * FF;
        const float* xr1 = Xt + (size_t)(1024 + tid) * FF;
        double s0 = 0.0, s1 = 0.0;
#pragma unroll
        for (int f = 0; f < 64; f += 4) {
            float4 v0 = *(const float4*)(xr0 + f);
            float4 v1 = *(const float4*)(xr1 + f);
            s0 += (double)v0.x * (double)scf[f]   + (double)v0.y * (double)scf[f+1]
                + (double)v0.z * (double)scf[f+2] + (double)v0.w * (double)scf[f+3];
            s1 += (double)v1.x * (double)scf[f]   + (double)v1.y * (double)scf[f+1]
                + (double)v1.z * (double)scf[f+2] + (double)v1.w * (double)scf[f+3];
        }
        ls0 = s0 * inv + (double)mask[t * NN + tid];
        ls1 = s1 * inv + (double)mask[t * NN + 1024 + tid];
    }

    // per-wave top-64 of its 128 elems (R17-proven)
    for (int r = 0; r < 64; ++r) {
        double bv; int bi;
        if (ls0 > ls1 || (ls0 == ls1)) { bv = ls0; bi = (w << 6) + lane; }
        else                           { bv = ls1; bi = 1024 + (w << 6) + lane; }
#pragma unroll
        for (int off = 1; off < 64; off <<= 1) {
            double ov = __shfl_xor(bv, off);
            int    oi = __shfl_xor(bi, off);
            if (ov > bv || (ov == bv && oi < bi)) { bv = ov; bi = oi; }
        }
        if (lane == 0) { sk[(w << 6) + r] = bv; si[(w << 6) + r] = bi; }
        if ((bi & 63) == lane) {
            if (bi < 1024) ls0 = -INFINITY; else ls1 = -INFINITY;
        }
    }
    __syncthreads();

    // bitonic sort 1024 candidates, best-first (R17-proven)
    for (int k = 2; k <= 1024; k <<= 1) {
        for (int jj = k >> 1; jj > 0; jj >>= 1) {
            const int i = tid, l = i ^ jj;
            if (l > i) {
                const double a = sk[i], b2 = sk[l];
                const int ai = si[i], bi2 = si[l];
                const bool ib = (a > b2) || (a == b2 && ai < bi2);
                const bool keep = ((i & k) == 0) ? ib : !ib;
                if (!keep) {
                    sk[i] = b2; sk[l] = a;
                    si[i] = bi2; si[l] = ai;
                }
            }
            __syncthreads();
        }
    }

    if (tid < 64) {
        tkidx[t * 64 + tid] = si[tid];
        tkval[t * 64 + tid] = tanhf((float)sk[tid]);
    }
}

// ---------------------------------------------------------------------------
// K_B qchain v5 (R17-proven verbatim): 64 blocks x 256.  Prefetch all 32
// z-rows -> precompute all W@z (parallel) -> serial loop on LDS+shuffles.
// Writes Qtr[t][j][f] bf16.
// ---------------------------------------------------------------------------
__global__ __launch_bounds__(256) void qchain_kernel(
    const float* __restrict__ Q0,
    const float* __restrict__ Uu, const float* __restrict__ Ur,
    const float* __restrict__ Uh,
    const float* __restrict__ Wu, const float* __restrict__ Wr,
    const float* __restrict__ Wh,
    const float* __restrict__ bu, const float* __restrict__ br,
    const float* __restrict__ bh,
    const int* __restrict__ tkidx, const float* __restrict__ tkval,
    const float* __restrict__ X, unsigned short* __restrict__ Qtr)
{
    const int j = blockIdx.x, tid = threadIdx.x;
    const int w = tid >> 6, l = tid & 63;
    const int i = (w << 4) + (l & 15);
    const int fq = l >> 4, fb = fq << 4;

    __shared__ __align__(16) float zsh[TT][64];
    __shared__ __align__(16) float wzl[3 * TT * 64];
    __shared__ __align__(16) float q[64];
    __shared__ __align__(16) float rr[64];

    {
        const int tt = tid >> 3, p8 = (tid & 7) << 3;
        const int idxt = tkidx[tt * 64 + j];
        const float th = tkval[tt * 64 + j];
        const float* xr = X + ((size_t)tt * NN + idxt) * FF + p8;
        float4 v0 = *(const float4*)(xr);
        float4 v1 = *(const float4*)(xr + 4);
        zsh[tt][p8]     = v0.x * th; zsh[tt][p8 + 1] = v0.y * th;
        zsh[tt][p8 + 2] = v0.z * th; zsh[tt][p8 + 3] = v0.w * th;
        zsh[tt][p8 + 4] = v1.x * th; zsh[tt][p8 + 5] = v1.y * th;
        zsh[tt][p8 + 6] = v1.z * th; zsh[tt][p8 + 7] = v1.w * th;
    }

    float uu[16], ur[16], uh[16], wu[16], wr[16], wh[16];
#pragma unroll
    for (int e = 0; e < 16; e += 4) {
        float4 a = *(const float4*)(Uu + i * 64 + fb + e);
        uu[e] = a.x; uu[e+1] = a.y; uu[e+2] = a.z; uu[e+3] = a.w;
        float4 c = *(const float4*)(Ur + i * 64 + fb + e);
        ur[e] = c.x; ur[e+1] = c.y; ur[e+2] = c.z; ur[e+3] = c.w;
        float4 d = *(const float4*)(Uh + i * 64 + fb + e);
        uh[e] = d.x; uh[e+1] = d.y; uh[e+2] = d.z; uh[e+3] = d.w;
        float4 p = *(const float4*)(Wu + i * 64 + fb + e);
        wu[e] = p.x; wu[e+1] = p.y; wu[e+2] = p.z; wu[e+3] = p.w;
        float4 s = *(const float4*)(Wr + i * 64 + fb + e);
        wr[e] = s.x; wr[e+1] = s.y; wr[e+2] = s.z; wr[e+3] = s.w;
        float4 g = *(const float4*)(Wh + i * 64 + fb + e);
        wh[e] = g.x; wh[e+1] = g.y; wh[e+2] = g.z; wh[e+3] = g.w;
    }
    const float bui = bu[i * 64 + j];
    const float bri = br[i * 64 + j];
    const float bhi = bh[i * 64 + j];
    if (tid < 64) q[tid] = Q0[tid * 64 + j];
    __syncthreads();

    for (int t = 0; t < TT; ++t) {
        float z16[16];
#pragma unroll
        for (int e = 0; e < 16; e += 4) {
            f32x4 z = *(const f32x4*)(&zsh[t][fb + e]);
            z16[e] = z[0]; z16[e+1] = z[1]; z16[e+2] = z[2]; z16[e+3] = z[3];
        }
        float pu = 0.f, pr = 0.f, ph = 0.f;
#pragma unroll
        for (int e = 0; e < 16; ++e) {
            pu += wu[e] * z16[e];
            pr += wr[e] * z16[e];
            ph += wh[e] * z16[e];
        }
        pu += __shfl_xor(pu, 16); pu += __shfl_xor(pu, 32);
        pr += __shfl_xor(pr, 16); pr += __shfl_xor(pr, 32);
        ph += __shfl_xor(ph, 16); ph += __shfl_xor(ph, 32);
        if (fq == 0) {
            wzl[(0 * TT + t) * 64 + i] = pu;
            wzl[(1 * TT + t) * 64 + i] = pr;
            wzl[(2 * TT + t) * 64 + i] = ph;
        }
    }
    __syncthreads();

    for (int t = 0; t < TT; ++t) {
        float q16[16];
#pragma unroll
        for (int e = 0; e < 16; e += 4) {
            f32x4 v = *(const f32x4*)(&q[fb + e]);
            q16[e] = v[0]; q16[e+1] = v[1]; q16[e+2] = v[2]; q16[e+3] = v[3];
        }
        float su = 0.f, sr = 0.f;
#pragma unroll
        for (int e = 0; e < 16; ++e) { su += uu[e] * q16[e]; sr += ur[e] * q16[e]; }
        su += __shfl_xor(su, 16); su += __shfl_xor(su, 32);
        sr += __shfl_xor(sr, 16); sr += __shfl_xor(sr, 32);
        const float u_ = 1.f / (1.f + expf(-(su + wzl[(0 * TT + t) * 64 + i] + bui)));
        const float r_ = 1.f / (1.f + expf(-(sr + wzl[(1 * TT + t) * 64 + i] + bri)));
        if (fq == 0) rr[i] = r_;
        __syncthreads();
        float sh = 0.f;
#pragma unroll
        for (int e = 0; e < 16; e += 4) {
            f32x4 v = *(const f32x4*)(&rr[fb + e]);
            sh += uh[e]   * (v[0] * q16[e]);
            sh += uh[e+1] * (v[1] * q16[e+1]);
            sh += uh[e+2] * (v[2] * q16[e+2]);
            sh += uh[e+3] * (v[3] * q16[e+3]);
        }
        sh += __shfl_xor(sh, 16); sh += __shfl_xor(sh, 32);
        float hv = sh + wzl[(2 * TT + t) * 64 + i] + bhi;
        hv = hv > 0.f ? hv : 0.f;
        const float qi = q[i];
        const float qn = (1.f - u_) * qi + u_ * hv;
        __syncthreads();
        if (fq == 0) {
            q[i] = qn;
            Qtr[(size_t)t * 4096 + j * 64 + i] = f2bf(qn);
        }
        __syncthreads();
    }
}

// ---------------------------------------------------------------------------
// K_C y-MFMA v2: B read from X f32 directly, cvt in reg (values identical
// to R17's Xbf path).  A = Qtr staged (R17-proven).  grid (8, 32) x 256.
// ---------------------------------------------------------------------------
__global__ __launch_bounds__(256) void ymfma_kernel(
    const float* __restrict__ X, const unsigned short* __restrict__ Qtr,
    unsigned short* __restrict__ Ytr)
{
    __shared__ __align__(16) unsigned char Qb[8192];   // bf16 [64 j][128B]
    const int t = blockIdx.y, tid = threadIdx.x;
    const int n0 = blockIdx.x * 256;
    const int lane = tid & 63, w = tid >> 6;
    const int lr = lane & 15, lq = lane >> 4;

    const unsigned short* Qp = Qtr + (size_t)t * 4096;
#pragma unroll
    for (int q2 = 0; q2 < 2; ++q2) {
        const int j = (w << 4) + (q2 << 3) + (lane >> 3);
        const unsigned short* g = Qp + (size_t)j * 64 + (((lane & 7) ^ (j & 7)) << 3);
        __builtin_amdgcn_global_load_lds(
            (const __attribute__((address_space(1))) void*)g,
            (__attribute__((address_space(3))) void*)
                (&Qb[((w << 4) + (q2 << 3)) << 7]), 16, 0, 0);
    }
    __syncthreads();

    f32x4 acc[4][4];
#pragma unroll
    for (int jt = 0; jt < 4; ++jt)
#pragma unroll
        for (int nt = 0; nt < 4; ++nt) acc[jt][nt] = (f32x4){0.f, 0.f, 0.f, 0.f};

#pragma unroll
    for (int ks = 0; ks < 2; ++ks) {
        bf16x8 af[4], bf[4];
#pragma unroll
        for (int jt = 0; jt < 4; ++jt) {
            const int j = (jt << 4) + lr;
            const int x = ((ks << 2) + lq) ^ (j & 7);
            af[jt] = *(const bf16x8*)(&Qb[(j << 7) + (x << 4)]);
        }
#pragma unroll
        for (int nt = 0; nt < 4; ++nt) {
            const int n = n0 + (w << 6) + (nt << 4) + lr;
            const float* xp = X + ((size_t)t * NN + n) * FF + (ks << 5) + (lq << 3);
            const float4 v0 = *(const float4*)(xp);
            const float4 v1 = *(const float4*)(xp + 4);
            bf[nt][0] = (__bf16)v0.x; bf[nt][1] = (__bf16)v0.y;
            bf[nt][2] = (__bf16)v0.z; bf[nt][3] = (__bf16)v0.w;
            bf[nt][4] = (__bf16)v1.x; bf[nt][5] = (__bf16)v1.y;
            bf[nt][6] = (__bf16)v1.z; bf[nt][7] = (__bf16)v1.w;
        }
#pragma unroll
        for (int jt = 0; jt < 4; ++jt)
#pragma unroll
            for (int nt = 0; nt < 4; ++nt)
                acc[jt][nt] = __builtin_amdgcn_mfma_f32_16x16x32_bf16(
                    af[jt], bf[nt], acc[jt][nt], 0, 0, 0);
    }

#pragma unroll
    for (int jt = 0; jt < 4; ++jt)
#pragma unroll
        for (int nt = 0; nt < 4; ++nt) {
            const int nn = n0 + (w << 6) + (nt << 4) + lr;
#pragma unroll
            for (int rg = 0; rg < 4; ++rg) {
                const int j = (jt << 4) + (lq << 2) + rg;
                Ytr[(size_t)t * FF * NN + (size_t)j * NN + nn] = f2bf(acc[jt][nt][rg]);
            }
        }
}

// ---------------------------------------------------------------------------
// K_D: out[t] = relu(A[t] @ Y[t]).  R10 gemm (measured 112us @ 4.6 TB/s).
// ---------------------------------------------------------------------------
__global__ __launch_bounds__(256, 4) void gemm_kernel(
    const float* __restrict__ A, const unsigned short* __restrict__ Ytr,
    float* __restrict__ out)
{
    __shared__ __align__(16) unsigned char Abuf[16384];  // f32 [64 r][256B]
    __shared__ __align__(16) unsigned char Bbuf[8192];   // bf16 [64 j][128B]
    const int tid = threadIdx.x;
    const int bid = blockIdx.x;
    const int xcd = bid & 7, li = bid >> 3;          // 8 XCDs x 128 blocks
    const int t = (xcd << 2) + (li >> 5);            // 4 timesteps per XCD
    const int m0 = (li & 31) * 64;
    const int lane = tid & 63, w = tid >> 6;
    const int lr = lane & 15, lq = lane >> 4;

    const float* Ap = A + (size_t)t * NN * NN + (size_t)m0 * NN;
    const unsigned short* Yp = Ytr + (size_t)t * FF * NN;

    f32x4 acc[4];
#pragma unroll
    for (int nt = 0; nt < 4; ++nt) acc[nt] = (f32x4){0.f, 0.f, 0.f, 0.f};

    for (int kt = 0; kt < 32; ++kt) {
        const int kk = kt << 6;
#pragma unroll
        for (int q = 0; q < 4; ++q) {
            const int row = (w << 4) + (q << 2) + lq;
            const float* g = Ap + (size_t)row * NN + kk + ((lr ^ (row & 7)) << 2);
            __builtin_amdgcn_global_load_lds(
                (const __attribute__((address_space(1))) void*)g,
                (__attribute__((address_space(3))) void*)
                    (&Abuf[((w << 4) + (q << 2)) << 8]), 16, 0, 0);
        }
#pragma unroll
        for (int q = 0; q < 2; ++q) {
            const int j = (w << 4) + (q << 3) + (lane >> 3);
            const unsigned short* g = Yp + (size_t)j * NN + kk
                                    + (((lane & 7) ^ (j & 7)) << 3);
            __builtin_amdgcn_global_load_lds(
                (const __attribute__((address_space(1))) void*)g,
                (__attribute__((address_space(3))) void*)
                    (&Bbuf[((w << 4) + (q << 3)) << 7]), 16, 0, 0);
        }
        __syncthreads();
#pragma unroll
        for (int ks = 0; ks < 2; ++ks) {
            const int r = (w << 4) + lr;
            const int c0 = ((ks << 3) + (lq << 1)) ^ (lr & 7);
            const int c1 = ((ks << 3) + (lq << 1) + 1) ^ (lr & 7);
            const f32x4 a0 = *(const f32x4*)(&Abuf[(r << 8) + (c0 << 4)]);
            const f32x4 a1 = *(const f32x4*)(&Abuf[(r << 8) + (c1 << 4)]);
            bf16x8 af;
            af[0] = (__bf16)a0[0]; af[1] = (__bf16)a0[1];
            af[2] = (__bf16)a0[2]; af[3] = (__bf16)a0[3];
            af[4] = (__bf16)a1[0]; af[5] = (__bf16)a1[1];
            af[6] = (__bf16)a1[2]; af[7] = (__bf16)a1[3];
#pragma unroll
            for (int nt = 0; nt < 4; ++nt) {
                const int j = (nt << 4) + lr;
                const int x = ((ks << 2) + lq) ^ (j & 7);
                const bf16x8 bf = *(const bf16x8*)(&Bbuf[(j << 7) + (x << 4)]);
                acc[nt] = __builtin_amdgcn_mfma_f32_16x16x32_bf16(
                    af, bf, acc[nt], 0, 0, 0);
            }
        }
        __syncthreads();
    }

#pragma unroll
    for (int nt = 0; nt < 4; ++nt) {
        const int row0 = m0 + (w << 4) + (lq << 2);
        const int col = (nt << 4) + lr;
#pragma unroll
        for (int rg = 0; rg < 4; ++rg) {
            const float v = acc[nt][rg];
            out[((size_t)t * NN + (row0 + rg)) * FF + col] = v > 0.f ? v : 0.f;
        }
    }
}

// ---------------------------------------------------------------------------
extern "C" void kernel_launch(void* const* d_in, const int* in_sizes, int n_in,
                              void* d_out, int out_size, void* d_ws, size_t ws_size,
                              hipStream_t stream) {
    const float* A      = (const float*)d_in[0];
    const float* X      = (const float*)d_in[1];
    const float* mask   = (const float*)d_in[2];
    const float* Q0     = (const float*)d_in[3];
    const float* scorer = (const float*)d_in[4];
    const float* Wu     = (const float*)d_in[5];
    const float* Uu     = (const float*)d_in[6];
    const float* bu     = (const float*)d_in[7];
    const float* Wr     = (const float*)d_in[8];
    const float* Ur     = (const float*)d_in[9];
    const float* br     = (const float*)d_in[10];
    const float* Wh     = (const float*)d_in[11];
    const float* Uh     = (const float*)d_in[12];
    const float* bh     = (const float*)d_in[13];
    float* out = (float*)d_out;

    float* ws = (float*)d_ws;
    int*    tkidx       = (int*)ws;                          // [32][64]
    float*  tkval       = ws + 2048;                         // [32][64]
    unsigned short* Qtr = (unsigned short*)(ws + 4096);      // [32][64][64] bf16
    unsigned short* Ytr = (unsigned short*)(ws + 69632);     // [32][64][2048] bf16

    selscore_kernel<<<TT, 1024, 0, stream>>>(X, mask, scorer, tkidx, tkval);
    qchain_kernel<<<FF, 256, 0, stream>>>(Q0, Uu, Ur, Uh, Wu, Wr, Wh,
                                          bu, br, bh, tkidx, tkval, X, Qtr);
    ymfma_kernel<<<dim3(8, TT), 256, 0, stream>>>(X, Qtr, Ytr);
    gemm_kernel<<<1024, 256, 0, stream>>>(A, Ytr, out);
}

// Round 20
// 253.752 us; speedup vs baseline: 1.0801x; 1.0748x over previous
//
#include <hip/hip_runtime.h>
#include <hip/hip_bf16.h>
#include <math.h>

#define TT 32
#define NN 2048
#define FF 64

typedef float f32x4 __attribute__((ext_vector_type(4)));
typedef __bf16 bf16x8 __attribute__((ext_vector_type(8)));
typedef unsigned short u16x8 __attribute__((ext_vector_type(8)));

__device__ __forceinline__ unsigned short f2bf(float f) {
    __bf16 h = (__bf16)f;
    return __builtin_bit_cast(unsigned short, h);
}

// ---------------------------------------------------------------------------
// K_S: wide scoring kernel. grid (8, 32) x 256.  (R17-proven verbatim)
// ---------------------------------------------------------------------------
__global__ __launch_bounds__(256) void score_kernel(
    const float* __restrict__ X, const float* __restrict__ mask,
    const float* __restrict__ scorer,
    double* __restrict__ scores, unsigned short* __restrict__ Xbf)
{
    const int t = blockIdx.y, tid = threadIdx.x;
    const int n = blockIdx.x * 256 + tid;
    __shared__ float scf[64];
    if (tid < 64) scf[tid] = scorer[tid];
    __syncthreads();

    double nrm = 0.0;
#pragma unroll
    for (int f = 0; f < 64; ++f) nrm += (double)scf[f] * (double)scf[f];
    const double inv = 1.0 / sqrt(nrm);

    const float* xr = X + ((size_t)t * NN + n) * FF;
    unsigned short* xo = Xbf + ((size_t)t * NN + n) * FF;
    double s = 0.0;
#pragma unroll
    for (int f = 0; f < 64; f += 4) {
        float4 v = *(const float4*)(xr + f);
        s += (double)v.x * (double)scf[f]   + (double)v.y * (double)scf[f+1]
           + (double)v.z * (double)scf[f+2] + (double)v.w * (double)scf[f+3];
        ushort4 pk = make_ushort4(f2bf(v.x), f2bf(v.y), f2bf(v.z), f2bf(v.w));
        *(ushort4*)(xo + f) = pk;
    }
    scores[t * NN + n] = s * inv + (double)mask[t * NN + n];
}

// ---------------------------------------------------------------------------
// K_A select: 32 blocks x 1024.  (R17-proven verbatim: per-wave top-64
// extraction + 1024-candidate bitonic, desc/idx-asc) -> (idx, tanh(val)).
// ---------------------------------------------------------------------------
__global__ __launch_bounds__(1024) void select_kernel(
    const double* __restrict__ scores,
    int* __restrict__ tkidx, float* __restrict__ tkval)
{
    const int t = blockIdx.x, tid = threadIdx.x;
    const int lane = tid & 63, w = tid >> 6;
    __shared__ double sk[1024];
    __shared__ int    si[1024];

    double ls0 = scores[t * NN + tid];
    double ls1 = scores[t * NN + 1024 + tid];

    for (int r = 0; r < 64; ++r) {
        double bv; int bi;
        if (ls0 > ls1 || (ls0 == ls1)) { bv = ls0; bi = (w << 6) + lane; }
        else                           { bv = ls1; bi = 1024 + (w << 6) + lane; }
#pragma unroll
        for (int off = 1; off < 64; off <<= 1) {
            double ov = __shfl_xor(bv, off);
            int    oi = __shfl_xor(bi, off);
            if (ov > bv || (ov == bv && oi < bi)) { bv = ov; bi = oi; }
        }
        if (lane == 0) { sk[(w << 6) + r] = bv; si[(w << 6) + r] = bi; }
        if ((bi & 63) == lane) {
            if (bi < 1024) ls0 = -INFINITY; else ls1 = -INFINITY;
        }
    }
    __syncthreads();

    for (int k = 2; k <= 1024; k <<= 1) {
        for (int jj = k >> 1; jj > 0; jj >>= 1) {
            const int i = tid, l = i ^ jj;
            if (l > i) {
                const double a = sk[i], b2 = sk[l];
                const int ai = si[i], bi2 = si[l];
                const bool ib = (a > b2) || (a == b2 && ai < bi2);
                const bool keep = ((i & k) == 0) ? ib : !ib;
                if (!keep) {
                    sk[i] = b2; sk[l] = a;
                    si[i] = bi2; si[l] = ai;
                }
            }
            __syncthreads();
        }
    }

    if (tid < 64) {
        tkidx[t * 64 + tid] = si[tid];
        tkval[t * 64 + tid] = tanhf((float)sk[tid]);
    }
}

// ---------------------------------------------------------------------------
// K_B qchain v6: R17 v5 with ONE change — q double-buffered (q[2][64]) so
// the serial loop needs 2 block barriers per step instead of 3.
// B1: rr ready (r->h dep).  B2: q[nxt]+Qtr written (next-step read + rr WAR).
// ---------------------------------------------------------------------------
__global__ __launch_bounds__(256) void qchain_kernel(
    const float* __restrict__ Q0,
    const float* __restrict__ Uu, const float* __restrict__ Ur,
    const float* __restrict__ Uh,
    const float* __restrict__ Wu, const float* __restrict__ Wr,
    const float* __restrict__ Wh,
    const float* __restrict__ bu, const float* __restrict__ br,
    const float* __restrict__ bh,
    const int* __restrict__ tkidx, const float* __restrict__ tkval,
    const float* __restrict__ X, unsigned short* __restrict__ Qtr)
{
    const int j = blockIdx.x, tid = threadIdx.x;
    const int w = tid >> 6, l = tid & 63;
    const int i = (w << 4) + (l & 15);
    const int fq = l >> 4, fb = fq << 4;

    __shared__ __align__(16) float zsh[TT][64];
    __shared__ __align__(16) float wzl[3 * TT * 64];
    __shared__ __align__(16) float qd[2][64];
    __shared__ __align__(16) float rr[64];

    {
        const int tt = tid >> 3, p8 = (tid & 7) << 3;
        const int idxt = tkidx[tt * 64 + j];
        const float th = tkval[tt * 64 + j];
        const float* xr = X + ((size_t)tt * NN + idxt) * FF + p8;
        float4 v0 = *(const float4*)(xr);
        float4 v1 = *(const float4*)(xr + 4);
        zsh[tt][p8]     = v0.x * th; zsh[tt][p8 + 1] = v0.y * th;
        zsh[tt][p8 + 2] = v0.z * th; zsh[tt][p8 + 3] = v0.w * th;
        zsh[tt][p8 + 4] = v1.x * th; zsh[tt][p8 + 5] = v1.y * th;
        zsh[tt][p8 + 6] = v1.z * th; zsh[tt][p8 + 7] = v1.w * th;
    }

    float uu[16], ur[16], uh[16], wu[16], wr[16], wh[16];
#pragma unroll
    for (int e = 0; e < 16; e += 4) {
        float4 a = *(const float4*)(Uu + i * 64 + fb + e);
        uu[e] = a.x; uu[e+1] = a.y; uu[e+2] = a.z; uu[e+3] = a.w;
        float4 c = *(const float4*)(Ur + i * 64 + fb + e);
        ur[e] = c.x; ur[e+1] = c.y; ur[e+2] = c.z; ur[e+3] = c.w;
        float4 d = *(const float4*)(Uh + i * 64 + fb + e);
        uh[e] = d.x; uh[e+1] = d.y; uh[e+2] = d.z; uh[e+3] = d.w;
        float4 p = *(const float4*)(Wu + i * 64 + fb + e);
        wu[e] = p.x; wu[e+1] = p.y; wu[e+2] = p.z; wu[e+3] = p.w;
        float4 s = *(const float4*)(Wr + i * 64 + fb + e);
        wr[e] = s.x; wr[e+1] = s.y; wr[e+2] = s.z; wr[e+3] = s.w;
        float4 g = *(const float4*)(Wh + i * 64 + fb + e);
        wh[e] = g.x; wh[e+1] = g.y; wh[e+2] = g.z; wh[e+3] = g.w;
    }
    const float bui = bu[i * 64 + j];
    const float bri = br[i * 64 + j];
    const float bhi = bh[i * 64 + j];
    if (tid < 64) qd[0][tid] = Q0[tid * 64 + j];
    __syncthreads();

    for (int t = 0; t < TT; ++t) {
        float z16[16];
#pragma unroll
        for (int e = 0; e < 16; e += 4) {
            f32x4 z = *(const f32x4*)(&zsh[t][fb + e]);
            z16[e] = z[0]; z16[e+1] = z[1]; z16[e+2] = z[2]; z16[e+3] = z[3];
        }
        float pu = 0.f, pr = 0.f, ph = 0.f;
#pragma unroll
        for (int e = 0; e < 16; ++e) {
            pu += wu[e] * z16[e];
            pr += wr[e] * z16[e];
            ph += wh[e] * z16[e];
        }
        pu += __shfl_xor(pu, 16); pu += __shfl_xor(pu, 32);
        pr += __shfl_xor(pr, 16); pr += __shfl_xor(pr, 32);
        ph += __shfl_xor(ph, 16); ph += __shfl_xor(ph, 32);
        if (fq == 0) {
            wzl[(0 * TT + t) * 64 + i] = pu;
            wzl[(1 * TT + t) * 64 + i] = pr;
            wzl[(2 * TT + t) * 64 + i] = ph;
        }
    }
    __syncthreads();

    int cur = 0;
    for (int t = 0; t < TT; ++t) {
        float q16[16];
#pragma unroll
        for (int e = 0; e < 16; e += 4) {
            f32x4 v = *(const f32x4*)(&qd[cur][fb + e]);
            q16[e] = v[0]; q16[e+1] = v[1]; q16[e+2] = v[2]; q16[e+3] = v[3];
        }
        float su = 0.f, sr = 0.f;
#pragma unroll
        for (int e = 0; e < 16; ++e) { su += uu[e] * q16[e]; sr += ur[e] * q16[e]; }
        su += __shfl_xor(su, 16); su += __shfl_xor(su, 32);
        sr += __shfl_xor(sr, 16); sr += __shfl_xor(sr, 32);
        const float u_ = 1.f / (1.f + expf(-(su + wzl[(0 * TT + t) * 64 + i] + bui)));
        const float r_ = 1.f / (1.f + expf(-(sr + wzl[(1 * TT + t) * 64 + i] + bri)));
        if (fq == 0) rr[i] = r_;
        __syncthreads();                       // B1: rr ready
        float sh = 0.f;
#pragma unroll
        for (int e = 0; e < 16; e += 4) {
            f32x4 v = *(const f32x4*)(&rr[fb + e]);
            sh += uh[e]   * (v[0] * q16[e]);
            sh += uh[e+1] * (v[1] * q16[e+1]);
            sh += uh[e+2] * (v[2] * q16[e+2]);
            sh += uh[e+3] * (v[3] * q16[e+3]);
        }
        sh += __shfl_xor(sh, 16); sh += __shfl_xor(sh, 32);
        float hv = sh + wzl[(2 * TT + t) * 64 + i] + bhi;
        hv = hv > 0.f ? hv : 0.f;
        const float qi = qd[cur][i];
        const float qn = (1.f - u_) * qi + u_ * hv;
        if (fq == 0) {
            qd[cur ^ 1][i] = qn;
            Qtr[(size_t)t * 4096 + j * 64 + i] = f2bf(qn);
        }
        __syncthreads();                       // B2: q[nxt] ready + rr WAR
        cur ^= 1;
    }
}

// ---------------------------------------------------------------------------
// K_C y-MFMA (R17-proven verbatim): Ytr[t][j][n] = bf16(Qtr[t][j].Xbf[t][n])
// ---------------------------------------------------------------------------
__global__ __launch_bounds__(256) void ymfma_kernel(
    const unsigned short* __restrict__ Xbf, const unsigned short* __restrict__ Qtr,
    unsigned short* __restrict__ Ytr)
{
    __shared__ __align__(16) unsigned char Qb[8192];   // bf16 [64 j][128B]
    const int t = blockIdx.y, tid = threadIdx.x;
    const int n0 = blockIdx.x * 256;
    const int lane = tid & 63, w = tid >> 6;
    const int lr = lane & 15, lq = lane >> 4;

    const unsigned short* Qp = Qtr + (size_t)t * 4096;
#pragma unroll
    for (int q2 = 0; q2 < 2; ++q2) {
        const int j = (w << 4) + (q2 << 3) + (lane >> 3);
        const unsigned short* g = Qp + (size_t)j * 64 + (((lane & 7) ^ (j & 7)) << 3);
        __builtin_amdgcn_global_load_lds(
            (const __attribute__((address_space(1))) void*)g,
            (__attribute__((address_space(3))) void*)
                (&Qb[((w << 4) + (q2 << 3)) << 7]), 16, 0, 0);
    }
    __syncthreads();

    f32x4 acc[4][4];
#pragma unroll
    for (int jt = 0; jt < 4; ++jt)
#pragma unroll
        for (int nt = 0; nt < 4; ++nt) acc[jt][nt] = (f32x4){0.f, 0.f, 0.f, 0.f};

#pragma unroll
    for (int ks = 0; ks < 2; ++ks) {
        bf16x8 af[4], bf[4];
#pragma unroll
        for (int jt = 0; jt < 4; ++jt) {
            const int j = (jt << 4) + lr;
            const int x = ((ks << 2) + lq) ^ (j & 7);
            af[jt] = *(const bf16x8*)(&Qb[(j << 7) + (x << 4)]);
        }
#pragma unroll
        for (int nt = 0; nt < 4; ++nt) {
            const int n = n0 + (w << 6) + (nt << 4) + lr;
            bf[nt] = __builtin_bit_cast(bf16x8,
                *(const uint4*)(Xbf + ((size_t)t * NN + n) * FF + (ks << 5) + (lq << 3)));
        }
#pragma unroll
        for (int jt = 0; jt < 4; ++jt)
#pragma unroll
            for (int nt = 0; nt < 4; ++nt)
                acc[jt][nt] = __builtin_amdgcn_mfma_f32_16x16x32_bf16(
                    af[jt], bf[nt], acc[jt][nt], 0, 0, 0);
    }

#pragma unroll
    for (int jt = 0; jt < 4; ++jt)
#pragma unroll
        for (int nt = 0; nt < 4; ++nt) {
            const int nn = n0 + (w << 6) + (nt << 4) + lr;
#pragma unroll
            for (int rg = 0; rg < 4; ++rg) {
                const int j = (jt << 4) + (lq << 2) + rg;
                Ytr[(size_t)t * FF * NN + (size_t)j * NN + nn] = f2bf(acc[jt][nt][rg]);
            }
        }
}

// ---------------------------------------------------------------------------
// K_D: out[t] = relu(A[t] @ Y[t]).  R10 gemm (measured 112us @ 4.6 TB/s).
// ---------------------------------------------------------------------------
__global__ __launch_bounds__(256, 4) void gemm_kernel(
    const float* __restrict__ A, const unsigned short* __restrict__ Ytr,
    float* __restrict__ out)
{
    __shared__ __align__(16) unsigned char Abuf[16384];  // f32 [64 r][256B]
    __shared__ __align__(16) unsigned char Bbuf[8192];   // bf16 [64 j][128B]
    const int tid = threadIdx.x;
    const int bid = blockIdx.x;
    const int xcd = bid & 7, li = bid >> 3;          // 8 XCDs x 128 blocks
    const int t = (xcd << 2) + (li >> 5);            // 4 timesteps per XCD
    const int m0 = (li & 31) * 64;
    const int lane = tid & 63, w = tid >> 6;
    const int lr = lane & 15, lq = lane >> 4;

    const float* Ap = A + (size_t)t * NN * NN + (size_t)m0 * NN;
    const unsigned short* Yp = Ytr + (size_t)t * FF * NN;

    f32x4 acc[4];
#pragma unroll
    for (int nt = 0; nt < 4; ++nt) acc[nt] = (f32x4){0.f, 0.f, 0.f, 0.f};

    for (int kt = 0; kt < 32; ++kt) {
        const int kk = kt << 6;
#pragma unroll
        for (int q = 0; q < 4; ++q) {
            const int row = (w << 4) + (q << 2) + lq;
            const float* g = Ap + (size_t)row * NN + kk + ((lr ^ (row & 7)) << 2);
            __builtin_amdgcn_global_load_lds(
                (const __attribute__((address_space(1))) void*)g,
                (__attribute__((address_space(3))) void*)
                    (&Abuf[((w << 4) + (q << 2)) << 8]), 16, 0, 0);
        }
#pragma unroll
        for (int q = 0; q < 2; ++q) {
            const int j = (w << 4) + (q << 3) + (lane >> 3);
            const unsigned short* g = Yp + (size_t)j * NN + kk
                                    + (((lane & 7) ^ (j & 7)) << 3);
            __builtin_amdgcn_global_load_lds(
                (const __attribute__((address_space(1))) void*)g,
                (__attribute__((address_space(3))) void*)
                    (&Bbuf[((w << 4) + (q << 3)) << 7]), 16, 0, 0);
        }
        __syncthreads();
#pragma unroll
        for (int ks = 0; ks < 2; ++ks) {
            const int r = (w << 4) + lr;
            const int c0 = ((ks << 3) + (lq << 1)) ^ (lr & 7);
            const int c1 = ((ks << 3) + (lq << 1) + 1) ^ (lr & 7);
            const f32x4 a0 = *(const f32x4*)(&Abuf[(r << 8) + (c0 << 4)]);
            const f32x4 a1 = *(const f32x4*)(&Abuf[(r << 8) + (c1 << 4)]);
            bf16x8 af;
            af[0] = (__bf16)a0[0]; af[1] = (__bf16)a0[1];
            af[2] = (__bf16)a0[2]; af[3] = (__bf16)a0[3];
            af[4] = (__bf16)a1[0]; af[5] = (__bf16)a1[1];
            af[6] = (__bf16)a1[2]; af[7] = (__bf16)a1[3];
#pragma unroll
            for (int nt = 0; nt < 4; ++nt) {
                const int j = (nt << 4) + lr;
                const int x = ((ks << 2) + lq) ^ (j & 7);
                const bf16x8 bf = *(const bf16x8*)(&Bbuf[(j << 7) + (x << 4)]);
                acc[nt] = __builtin_amdgcn_mfma_f32_16x16x32_bf16(
                    af, bf, acc[nt], 0, 0, 0);
            }
        }
        __syncthreads();
    }

#pragma unroll
    for (int nt = 0; nt < 4; ++nt) {
        const int row0 = m0 + (w << 4) + (lq << 2);
        const int col = (nt << 4) + lr;
#pragma unroll
        for (int rg = 0; rg < 4; ++rg) {
            const float v = acc[nt][rg];
            out[((size_t)t * NN + (row0 + rg)) * FF + col] = v > 0.f ? v : 0.f;
        }
    }
}

// ---------------------------------------------------------------------------
extern "C" void kernel_launch(void* const* d_in, const int* in_sizes, int n_in,
                              void* d_out, int out_size, void* d_ws, size_t ws_size,
                              hipStream_t stream) {
    const float* A      = (const float*)d_in[0];
    const float* X      = (const float*)d_in[1];
    const float* mask   = (const float*)d_in[2];
    const float* Q0     = (const float*)d_in[3];
    const float* scorer = (const float*)d_in[4];
    const float* Wu     = (const float*)d_in[5];
    const float* Uu     = (const float*)d_in[6];
    const float* bu     = (const float*)d_in[7];
    const float* Wr     = (const float*)d_in[8];
    const float* Ur     = (const float*)d_in[9];
    const float* br     = (const float*)d_in[10];
    const float* Wh     = (const float*)d_in[11];
    const float* Uh     = (const float*)d_in[12];
    const float* bh     = (const float*)d_in[13];
    float* out = (float*)d_out;

    float* ws = (float*)d_ws;
    double* scores        = (double*)ws;                          // [32][2048] fp64
    int*    tkidx         = (int*)(ws + 131072);                  // [32][64]
    float*  tkval         = ws + 133120;                          // [32][64]
    unsigned short* Qtr   = (unsigned short*)(ws + 135168);       // [32][64][64] bf16
    unsigned short* Xbf   = (unsigned short*)(ws + 200704);       // [32][2048][64] bf16
    unsigned short* Ytr   = (unsigned short*)(ws + 2297856);      // [32][64][2048] bf16

    score_kernel<<<dim3(8, TT), 256, 0, stream>>>(X, mask, scorer, scores, Xbf);
    select_kernel<<<TT, 1024, 0, stream>>>(scores, tkidx, tkval);
    qchain_kernel<<<FF, 256, 0, stream>>>(Q0, Uu, Ur, Uh, Wu, Wr, Wh,
                                          bu, br, bh, tkidx, tkval, X, Qtr);
    ymfma_kernel<<<dim3(8, TT), 256, 0, stream>>>(Xbf, Qtr, Ytr);
    gemm_kernel<<<1024, 256, 0, stream>>>(A, Ytr, out);
}

// Round 21
// 203.629 us; speedup vs baseline: 1.3460x; 1.2462x over previous
//
#include <hip/hip_runtime.h>
#include <hip/hip_bf16.h>
#include <math.h>

#define TT 32
#define NN 2048
#define FF 64

typedef float f32x4 __attribute__((ext_vector_type(4)));
typedef __bf16 bf16x8 __attribute__((ext_vector_type(8)));
typedef unsigned short u16x8 __attribute__((ext_vector_type(8)));

__device__ __forceinline__ unsigned short f2bf(float f) {
    __bf16 h = (__bf16)f;
    return __builtin_bit_cast(unsigned short, h);
}

// ---------------------------------------------------------------------------
// K_S: wide scoring kernel. grid (8, 32) x 256.  (R17/R20-proven verbatim)
// ---------------------------------------------------------------------------
__global__ __launch_bounds__(256) void score_kernel(
    const float* __restrict__ X, const float* __restrict__ mask,
    const float* __restrict__ scorer,
    double* __restrict__ scores, unsigned short* __restrict__ Xbf)
{
    const int t = blockIdx.y, tid = threadIdx.x;
    const int n = blockIdx.x * 256 + tid;
    __shared__ float scf[64];
    if (tid < 64) scf[tid] = scorer[tid];
    __syncthreads();

    double nrm = 0.0;
#pragma unroll
    for (int f = 0; f < 64; ++f) nrm += (double)scf[f] * (double)scf[f];
    const double inv = 1.0 / sqrt(nrm);

    const float* xr = X + ((size_t)t * NN + n) * FF;
    unsigned short* xo = Xbf + ((size_t)t * NN + n) * FF;
    double s = 0.0;
#pragma unroll
    for (int f = 0; f < 64; f += 4) {
        float4 v = *(const float4*)(xr + f);
        s += (double)v.x * (double)scf[f]   + (double)v.y * (double)scf[f+1]
           + (double)v.z * (double)scf[f+2] + (double)v.w * (double)scf[f+3];
        ushort4 pk = make_ushort4(f2bf(v.x), f2bf(v.y), f2bf(v.z), f2bf(v.w));
        *(ushort4*)(xo + f) = pk;
    }
    scores[t * NN + n] = s * inv + (double)mask[t * NN + n];
}

// ---------------------------------------------------------------------------
// K_A select v3: 32 blocks x 1024.  Per-wave FULL 128-elem in-register
// bitonic sort (2 elems/lane; e = r*64+lane; j==64 substage = local
// reg0<->reg1 compare, j<64 = shfl_xor; best-first, idx-asc ties) ->
// wave's sorted top-64 = reg0 across lanes -> 1024-candidate bitonic
// (R17-proven verbatim) -> (idx, tanh(val)).
// ---------------------------------------------------------------------------
__global__ __launch_bounds__(1024) void select_kernel(
    const double* __restrict__ scores,
    int* __restrict__ tkidx, float* __restrict__ tkval)
{
    const int t = blockIdx.x, tid = threadIdx.x;
    const int lane = tid & 63, w = tid >> 6;
    __shared__ double sk[1024];
    __shared__ int    si[1024];

    // wave w owns global rows [w*128, w*128+128): e = r*64+lane -> n = w*128+e
    double v0 = scores[t * NN + (w << 7) + lane];
    double v1 = scores[t * NN + (w << 7) + 64 + lane];
    int    i0 = (w << 7) + lane;
    int    i1 = (w << 7) + 64 + lane;

#define BETTER(av, ai, bv, bi) ((av) > (bv) || ((av) == (bv) && (ai) < (bi)))
    // full bitonic sort of 128 elems, best-first
#pragma unroll
    for (int k = 2; k <= 128; k <<= 1) {
#pragma unroll
        for (int j = 64; j > 0; j >>= 1) {
            if (j > (k >> 1)) continue;
            if (j == 64) {
                // local pair: e0 = lane (lower), e1 = 64+lane. k==128 -> up both.
                const bool ib = BETTER(v0, i0, v1, i1);
                if (!ib) {
                    const double tv = v0; v0 = v1; v1 = tv;
                    const int ti = i0; i0 = i1; i1 = ti;
                }
            } else {
                // reg 0: e = lane
                {
                    const double pv = __shfl_xor(v0, j);
                    const int    pi = __shfl_xor(i0, j);
                    const bool lower = (lane & j) == 0;
                    const bool up = ((lane & k) == 0);   // e&k, bit6 of e is 0
                    const bool ib = BETTER(v0, i0, pv, pi);
                    const bool keep = (up == lower) ? ib : !ib;
                    if (!keep) { v0 = pv; i0 = pi; }
                }
                // reg 1: e = 64+lane  (e&k differs from lane&k only at k==64)
                {
                    const double pv = __shfl_xor(v1, j);
                    const int    pi = __shfl_xor(i1, j);
                    const bool lower = (lane & j) == 0;
                    const bool up = (k == 64) ? false : ((lane & k) == 0);
                    const bool ib = BETTER(v1, i1, pv, pi);
                    const bool keep = (up == lower) ? ib : !ib;
                    if (!keep) { v1 = pv; i1 = pi; }
                }
            }
        }
    }
#undef BETTER
    // sorted best-first: e=0..63 (reg0, lane-ordered) are the wave's top-64
    sk[(w << 6) + lane] = v0;
    si[(w << 6) + lane] = i0;
    __syncthreads();

    // bitonic sort 1024 candidates, best-first (R17-proven verbatim)
    for (int k = 2; k <= 1024; k <<= 1) {
        for (int jj = k >> 1; jj > 0; jj >>= 1) {
            const int i = tid, l = i ^ jj;
            if (l > i) {
                const double a = sk[i], b2 = sk[l];
                const int ai = si[i], bi2 = si[l];
                const bool ib = (a > b2) || (a == b2 && ai < bi2);
                const bool keep = ((i & k) == 0) ? ib : !ib;
                if (!keep) {
                    sk[i] = b2; sk[l] = a;
                    si[i] = bi2; si[l] = ai;
                }
            }
            __syncthreads();
        }
    }

    if (tid < 64) {
        tkidx[t * 64 + tid] = si[tid];
        tkval[t * 64 + tid] = tanhf((float)sk[tid]);
    }
}

// ---------------------------------------------------------------------------
// K_B qchain v6 (R20-proven verbatim): 64 blocks x 256, 2 barriers/step.
// ---------------------------------------------------------------------------
__global__ __launch_bounds__(256) void qchain_kernel(
    const float* __restrict__ Q0,
    const float* __restrict__ Uu, const float* __restrict__ Ur,
    const float* __restrict__ Uh,
    const float* __restrict__ Wu, const float* __restrict__ Wr,
    const float* __restrict__ Wh,
    const float* __restrict__ bu, const float* __restrict__ br,
    const float* __restrict__ bh,
    const int* __restrict__ tkidx, const float* __restrict__ tkval,
    const float* __restrict__ X, unsigned short* __restrict__ Qtr)
{
    const int j = blockIdx.x, tid = threadIdx.x;
    const int w = tid >> 6, l = tid & 63;
    const int i = (w << 4) + (l & 15);
    const int fq = l >> 4, fb = fq << 4;

    __shared__ __align__(16) float zsh[TT][64];
    __shared__ __align__(16) float wzl[3 * TT * 64];
    __shared__ __align__(16) float qd[2][64];
    __shared__ __align__(16) float rr[64];

    {
        const int tt = tid >> 3, p8 = (tid & 7) << 3;
        const int idxt = tkidx[tt * 64 + j];
        const float th = tkval[tt * 64 + j];
        const float* xr = X + ((size_t)tt * NN + idxt) * FF + p8;
        float4 v0 = *(const float4*)(xr);
        float4 v1 = *(const float4*)(xr + 4);
        zsh[tt][p8]     = v0.x * th; zsh[tt][p8 + 1] = v0.y * th;
        zsh[tt][p8 + 2] = v0.z * th; zsh[tt][p8 + 3] = v0.w * th;
        zsh[tt][p8 + 4] = v1.x * th; zsh[tt][p8 + 5] = v1.y * th;
        zsh[tt][p8 + 6] = v1.z * th; zsh[tt][p8 + 7] = v1.w * th;
    }

    float uu[16], ur[16], uh[16], wu[16], wr[16], wh[16];
#pragma unroll
    for (int e = 0; e < 16; e += 4) {
        float4 a = *(const float4*)(Uu + i * 64 + fb + e);
        uu[e] = a.x; uu[e+1] = a.y; uu[e+2] = a.z; uu[e+3] = a.w;
        float4 c = *(const float4*)(Ur + i * 64 + fb + e);
        ur[e] = c.x; ur[e+1] = c.y; ur[e+2] = c.z; ur[e+3] = c.w;
        float4 d = *(const float4*)(Uh + i * 64 + fb + e);
        uh[e] = d.x; uh[e+1] = d.y; uh[e+2] = d.z; uh[e+3] = d.w;
        float4 p = *(const float4*)(Wu + i * 64 + fb + e);
        wu[e] = p.x; wu[e+1] = p.y; wu[e+2] = p.z; wu[e+3] = p.w;
        float4 s = *(const float4*)(Wr + i * 64 + fb + e);
        wr[e] = s.x; wr[e+1] = s.y; wr[e+2] = s.z; wr[e+3] = s.w;
        float4 g = *(const float4*)(Wh + i * 64 + fb + e);
        wh[e] = g.x; wh[e+1] = g.y; wh[e+2] = g.z; wh[e+3] = g.w;
    }
    const float bui = bu[i * 64 + j];
    const float bri = br[i * 64 + j];
    const float bhi = bh[i * 64 + j];
    if (tid < 64) qd[0][tid] = Q0[tid * 64 + j];
    __syncthreads();

    for (int t = 0; t < TT; ++t) {
        float z16[16];
#pragma unroll
        for (int e = 0; e < 16; e += 4) {
            f32x4 z = *(const f32x4*)(&zsh[t][fb + e]);
            z16[e] = z[0]; z16[e+1] = z[1]; z16[e+2] = z[2]; z16[e+3] = z[3];
        }
        float pu = 0.f, pr = 0.f, ph = 0.f;
#pragma unroll
        for (int e = 0; e < 16; ++e) {
            pu += wu[e] * z16[e];
            pr += wr[e] * z16[e];
            ph += wh[e] * z16[e];
        }
        pu += __shfl_xor(pu, 16); pu += __shfl_xor(pu, 32);
        pr += __shfl_xor(pr, 16); pr += __shfl_xor(pr, 32);
        ph += __shfl_xor(ph, 16); ph += __shfl_xor(ph, 32);
        if (fq == 0) {
            wzl[(0 * TT + t) * 64 + i] = pu;
            wzl[(1 * TT + t) * 64 + i] = pr;
            wzl[(2 * TT + t) * 64 + i] = ph;
        }
    }
    __syncthreads();

    int cur = 0;
    for (int t = 0; t < TT; ++t) {
        float q16[16];
#pragma unroll
        for (int e = 0; e < 16; e += 4) {
            f32x4 v = *(const f32x4*)(&qd[cur][fb + e]);
            q16[e] = v[0]; q16[e+1] = v[1]; q16[e+2] = v[2]; q16[e+3] = v[3];
        }
        float su = 0.f, sr = 0.f;
#pragma unroll
        for (int e = 0; e < 16; ++e) { su += uu[e] * q16[e]; sr += ur[e] * q16[e]; }
        su += __shfl_xor(su, 16); su += __shfl_xor(su, 32);
        sr += __shfl_xor(sr, 16); sr += __shfl_xor(sr, 32);
        const float u_ = 1.f / (1.f + expf(-(su + wzl[(0 * TT + t) * 64 + i] + bui)));
        const float r_ = 1.f / (1.f + expf(-(sr + wzl[(1 * TT + t) * 64 + i] + bri)));
        if (fq == 0) rr[i] = r_;
        __syncthreads();                       // B1: rr ready
        float sh = 0.f;
#pragma unroll
        for (int e = 0; e < 16; e += 4) {
            f32x4 v = *(const f32x4*)(&rr[fb + e]);
            sh += uh[e]   * (v[0] * q16[e]);
            sh += uh[e+1] * (v[1] * q16[e+1]);
            sh += uh[e+2] * (v[2] * q16[e+2]);
            sh += uh[e+3] * (v[3] * q16[e+3]);
        }
        sh += __shfl_xor(sh, 16); sh += __shfl_xor(sh, 32);
        float hv = sh + wzl[(2 * TT + t) * 64 + i] + bhi;
        hv = hv > 0.f ? hv : 0.f;
        const float qi = qd[cur][i];
        const float qn = (1.f - u_) * qi + u_ * hv;
        if (fq == 0) {
            qd[cur ^ 1][i] = qn;
            Qtr[(size_t)t * 4096 + j * 64 + i] = f2bf(qn);
        }
        __syncthreads();                       // B2: q[nxt] ready + rr WAR
        cur ^= 1;
    }
}

// ---------------------------------------------------------------------------
// K_C y-MFMA (R17-proven verbatim): Ytr[t][j][n] = bf16(Qtr[t][j].Xbf[t][n])
// ---------------------------------------------------------------------------
__global__ __launch_bounds__(256) void ymfma_kernel(
    const unsigned short* __restrict__ Xbf, const unsigned short* __restrict__ Qtr,
    unsigned short* __restrict__ Ytr)
{
    __shared__ __align__(16) unsigned char Qb[8192];   // bf16 [64 j][128B]
    const int t = blockIdx.y, tid = threadIdx.x;
    const int n0 = blockIdx.x * 256;
    const int lane = tid & 63, w = tid >> 6;
    const int lr = lane & 15, lq = lane >> 4;

    const unsigned short* Qp = Qtr + (size_t)t * 4096;
#pragma unroll
    for (int q2 = 0; q2 < 2; ++q2) {
        const int j = (w << 4) + (q2 << 3) + (lane >> 3);
        const unsigned short* g = Qp + (size_t)j * 64 + (((lane & 7) ^ (j & 7)) << 3);
        __builtin_amdgcn_global_load_lds(
            (const __attribute__((address_space(1))) void*)g,
            (__attribute__((address_space(3))) void*)
                (&Qb[((w << 4) + (q2 << 3)) << 7]), 16, 0, 0);
    }
    __syncthreads();

    f32x4 acc[4][4];
#pragma unroll
    for (int jt = 0; jt < 4; ++jt)
#pragma unroll
        for (int nt = 0; nt < 4; ++nt) acc[jt][nt] = (f32x4){0.f, 0.f, 0.f, 0.f};

#pragma unroll
    for (int ks = 0; ks < 2; ++ks) {
        bf16x8 af[4], bf[4];
#pragma unroll
        for (int jt = 0; jt < 4; ++jt) {
            const int j = (jt << 4) + lr;
            const int x = ((ks << 2) + lq) ^ (j & 7);
            af[jt] = *(const bf16x8*)(&Qb[(j << 7) + (x << 4)]);
        }
#pragma unroll
        for (int nt = 0; nt < 4; ++nt) {
            const int n = n0 + (w << 6) + (nt << 4) + lr;
            bf[nt] = __builtin_bit_cast(bf16x8,
                *(const uint4*)(Xbf + ((size_t)t * NN + n) * FF + (ks << 5) + (lq << 3)));
        }
#pragma unroll
        for (int jt = 0; jt < 4; ++jt)
#pragma unroll
            for (int nt = 0; nt < 4; ++nt)
                acc[jt][nt] = __builtin_amdgcn_mfma_f32_16x16x32_bf16(
                    af[jt], bf[nt], acc[jt][nt], 0, 0, 0);
    }

#pragma unroll
    for (int jt = 0; jt < 4; ++jt)
#pragma unroll
        for (int nt = 0; nt < 4; ++nt) {
            const int nn = n0 + (w << 6) + (nt << 4) + lr;
#pragma unroll
            for (int rg = 0; rg < 4; ++rg) {
                const int j = (jt << 4) + (lq << 2) + rg;
                Ytr[(size_t)t * FF * NN + (size_t)j * NN + nn] = f2bf(acc[jt][nt][rg]);
            }
        }
}

// ---------------------------------------------------------------------------
// K_D: out[t] = relu(A[t] @ Y[t]).  R10 gemm (measured 112us @ 4.6 TB/s).
// ---------------------------------------------------------------------------
__global__ __launch_bounds__(256, 4) void gemm_kernel(
    const float* __restrict__ A, const unsigned short* __restrict__ Ytr,
    float* __restrict__ out)
{
    __shared__ __align__(16) unsigned char Abuf[16384];  // f32 [64 r][256B]
    __shared__ __align__(16) unsigned char Bbuf[8192];   // bf16 [64 j][128B]
    const int tid = threadIdx.x;
    const int bid = blockIdx.x;
    const int xcd = bid & 7, li = bid >> 3;          // 8 XCDs x 128 blocks
    const int t = (xcd << 2) + (li >> 5);            // 4 timesteps per XCD
    const int m0 = (li & 31) * 64;
    const int lane = tid & 63, w = tid >> 6;
    const int lr = lane & 15, lq = lane >> 4;

    const float* Ap = A + (size_t)t * NN * NN + (size_t)m0 * NN;
    const unsigned short* Yp = Ytr + (size_t)t * FF * NN;

    f32x4 acc[4];
#pragma unroll
    for (int nt = 0; nt < 4; ++nt) acc[nt] = (f32x4){0.f, 0.f, 0.f, 0.f};

    for (int kt = 0; kt < 32; ++kt) {
        const int kk = kt << 6;
#pragma unroll
        for (int q = 0; q < 4; ++q) {
            const int row = (w << 4) + (q << 2) + lq;
            const float* g = Ap + (size_t)row * NN + kk + ((lr ^ (row & 7)) << 2);
            __builtin_amdgcn_global_load_lds(
                (const __attribute__((address_space(1))) void*)g,
                (__attribute__((address_space(3))) void*)
                    (&Abuf[((w << 4) + (q << 2)) << 8]), 16, 0, 0);
        }
#pragma unroll
        for (int q = 0; q < 2; ++q) {
            const int j = (w << 4) + (q << 3) + (lane >> 3);
            const unsigned short* g = Yp + (size_t)j * NN + kk
                                    + (((lane & 7) ^ (j & 7)) << 3);
            __builtin_amdgcn_global_load_lds(
                (const __attribute__((address_space(1))) void*)g,
                (__attribute__((address_space(3))) void*)
                    (&Bbuf[((w << 4) + (q << 3)) << 7]), 16, 0, 0);
        }
        __syncthreads();
#pragma unroll
        for (int ks = 0; ks < 2; ++ks) {
            const int r = (w << 4) + lr;
            const int c0 = ((ks << 3) + (lq << 1)) ^ (lr & 7);
            const int c1 = ((ks << 3) + (lq << 1) + 1) ^ (lr & 7);
            const f32x4 a0 = *(const f32x4*)(&Abuf[(r << 8) + (c0 << 4)]);
            const f32x4 a1 = *(const f32x4*)(&Abuf[(r << 8) + (c1 << 4)]);
            bf16x8 af;
            af[0] = (__bf16)a0[0]; af[1] = (__bf16)a0[1];
            af[2] = (__bf16)a0[2]; af[3] = (__bf16)a0[3];
            af[4] = (__bf16)a1[0]; af[5] = (__bf16)a1[1];
            af[6] = (__bf16)a1[2]; af[7] = (__bf16)a1[3];
#pragma unroll
            for (int nt = 0; nt < 4; ++nt) {
                const int j = (nt << 4) + lr;
                const int x = ((ks << 2) + lq) ^ (j & 7);
                const bf16x8 bf = *(const bf16x8*)(&Bbuf[(j << 7) + (x << 4)]);
                acc[nt] = __builtin_amdgcn_mfma_f32_16x16x32_bf16(
                    af, bf, acc[nt], 0, 0, 0);
            }
        }
        __syncthreads();
    }

#pragma unroll
    for (int nt = 0; nt < 4; ++nt) {
        const int row0 = m0 + (w << 4) + (lq << 2);
        const int col = (nt << 4) + lr;
#pragma unroll
        for (int rg = 0; rg < 4; ++rg) {
            const float v = acc[nt][rg];
            out[((size_t)t * NN + (row0 + rg)) * FF + col] = v > 0.f ? v : 0.f;
        }
    }
}

// ---------------------------------------------------------------------------
extern "C" void kernel_launch(void* const* d_in, const int* in_sizes, int n_in,
                              void* d_out, int out_size, void* d_ws, size_t ws_size,
                              hipStream_t stream) {
    const float* A      = (const float*)d_in[0];
    const float* X      = (const float*)d_in[1];
    const float* mask   = (const float*)d_in[2];
    const float* Q0     = (const float*)d_in[3];
    const float* scorer = (const float*)d_in[4];
    const float* Wu     = (const float*)d_in[5];
    const float* Uu     = (const float*)d_in[6];
    const float* bu     = (const float*)d_in[7];
    const float* Wr     = (const float*)d_in[8];
    const float* Ur     = (const float*)d_in[9];
    const float* br     = (const float*)d_in[10];
    const float* Wh     = (const float*)d_in[11];
    const float* Uh     = (const float*)d_in[12];
    const float* bh     = (const float*)d_in[13];
    float* out = (float*)d_out;

    float* ws = (float*)d_ws;
    double* scores        = (double*)ws;                          // [32][2048] fp64
    int*    tkidx         = (int*)(ws + 131072);                  // [32][64]
    float*  tkval         = ws + 133120;                          // [32][64]
    unsigned short* Qtr   = (unsigned short*)(ws + 135168);       // [32][64][64] bf16
    unsigned short* Xbf   = (unsigned short*)(ws + 200704);       // [32][2048][64] bf16
    unsigned short* Ytr   = (unsigned short*)(ws + 2297856);      // [32][64][2048] bf16

    score_kernel<<<dim3(8, TT), 256, 0, stream>>>(X, mask, scorer, scores, Xbf);
    select_kernel<<<TT, 1024, 0, stream>>>(scores, tkidx, tkval);
    qchain_kernel<<<FF, 256, 0, stream>>>(Q0, Uu, Ur, Uh, Wu, Wr, Wh,
                                          bu, br, bh, tkidx, tkval, X, Qtr);
    ymfma_kernel<<<dim3(8, TT), 256, 0, stream>>>(Xbf, Qtr, Ytr);
    gemm_kernel<<<1024, 256, 0, stream>>>(A, Ytr, out);
}

// Round 22
// 190.946 us; speedup vs baseline: 1.4354x; 1.0664x over previous
//
#include <hip/hip_runtime.h>
#include <hip/hip_bf16.h>
#include <math.h>

#define TT 32
#define NN 2048
#define FF 64

typedef float f32x4 __attribute__((ext_vector_type(4)));
typedef __bf16 bf16x8 __attribute__((ext_vector_type(8)));
typedef unsigned short u16x8 __attribute__((ext_vector_type(8)));

__device__ __forceinline__ unsigned short f2bf(float f) {
    __bf16 h = (__bf16)f;
    return __builtin_bit_cast(unsigned short, h);
}

// ---------------------------------------------------------------------------
// K_S: wide scoring kernel. grid (8, 32) x 256.  (R17/R21-proven verbatim)
// ---------------------------------------------------------------------------
__global__ __launch_bounds__(256) void score_kernel(
    const float* __restrict__ X, const float* __restrict__ mask,
    const float* __restrict__ scorer,
    double* __restrict__ scores, unsigned short* __restrict__ Xbf)
{
    const int t = blockIdx.y, tid = threadIdx.x;
    const int n = blockIdx.x * 256 + tid;
    __shared__ float scf[64];
    if (tid < 64) scf[tid] = scorer[tid];
    __syncthreads();

    double nrm = 0.0;
#pragma unroll
    for (int f = 0; f < 64; ++f) nrm += (double)scf[f] * (double)scf[f];
    const double inv = 1.0 / sqrt(nrm);

    const float* xr = X + ((size_t)t * NN + n) * FF;
    unsigned short* xo = Xbf + ((size_t)t * NN + n) * FF;
    double s = 0.0;
#pragma unroll
    for (int f = 0; f < 64; f += 4) {
        float4 v = *(const float4*)(xr + f);
        s += (double)v.x * (double)scf[f]   + (double)v.y * (double)scf[f+1]
           + (double)v.z * (double)scf[f+2] + (double)v.w * (double)scf[f+3];
        ushort4 pk = make_ushort4(f2bf(v.x), f2bf(v.y), f2bf(v.z), f2bf(v.w));
        *(ushort4*)(xo + f) = pk;
    }
    scores[t * NN + n] = s * inv + (double)mask[t * NN + n];
}

// ---------------------------------------------------------------------------
// K_A select v4: 32 blocks x 1024.
// Per-wave full 128-elem in-register bitonic sort (R21-proven) -> 16 sorted
// lists of 64 -> bitonic MERGE-AND-TRUNCATE tree (4 rounds; per round a
// wave half-cleans {list 2w, reversed list 2w+1} and re-sorts via 6
// shfl_xor substages).  Same strict total order (score desc, idx asc)
// => identical top-64 sequence to the full 1024 bitonic, 8 barriers vs 55.
// ---------------------------------------------------------------------------
__global__ __launch_bounds__(1024) void select_kernel(
    const double* __restrict__ scores,
    int* __restrict__ tkidx, float* __restrict__ tkval)
{
    const int t = blockIdx.x, tid = threadIdx.x;
    const int lane = tid & 63, w = tid >> 6;
    __shared__ double sk[1024];
    __shared__ int    si[1024];

    // wave w owns global rows [w*128, w*128+128): e = r*64+lane
    double v0 = scores[t * NN + (w << 7) + lane];
    double v1 = scores[t * NN + (w << 7) + 64 + lane];
    int    i0 = (w << 7) + lane;
    int    i1 = (w << 7) + 64 + lane;

#define BETTER(av, ai, bv, bi) ((av) > (bv) || ((av) == (bv) && (ai) < (bi)))
    // full bitonic sort of 128 elems, best-first (R21-proven)
#pragma unroll
    for (int k = 2; k <= 128; k <<= 1) {
#pragma unroll
        for (int j = 64; j > 0; j >>= 1) {
            if (j > (k >> 1)) continue;
            if (j == 64) {
                const bool ib = BETTER(v0, i0, v1, i1);
                if (!ib) {
                    const double tv = v0; v0 = v1; v1 = tv;
                    const int ti = i0; i0 = i1; i1 = ti;
                }
            } else {
                {
                    const double pv = __shfl_xor(v0, j);
                    const int    pi = __shfl_xor(i0, j);
                    const bool lower = (lane & j) == 0;
                    const bool up = ((lane & k) == 0);
                    const bool ib = BETTER(v0, i0, pv, pi);
                    const bool keep = (up == lower) ? ib : !ib;
                    if (!keep) { v0 = pv; i0 = pi; }
                }
                {
                    const double pv = __shfl_xor(v1, j);
                    const int    pi = __shfl_xor(i1, j);
                    const bool lower = (lane & j) == 0;
                    const bool up = (k == 64) ? false : ((lane & k) == 0);
                    const bool ib = BETTER(v1, i1, pv, pi);
                    const bool keep = (up == lower) ? ib : !ib;
                    if (!keep) { v1 = pv; i1 = pi; }
                }
            }
        }
    }
    // wave's sorted top-64 (best-first) = reg0 across lanes
    sk[(w << 6) + lane] = v0;
    si[(w << 6) + lane] = i0;
    __syncthreads();

    // merge-and-truncate tree: 16 -> 8 -> 4 -> 2 -> 1 lists
#pragma unroll
    for (int round = 0; round < 4; ++round) {
        const int nl = 8 >> round;          // merging waves this round
        double cv = 0.0; int ci = 0;
        const bool active = (w < nl);
        if (active) {
            const int la = (w << 1), lb = (w << 1) + 1;
            const double av = sk[(la << 6) + lane];
            const int    ai = si[(la << 6) + lane];
            const double bv = sk[(lb << 6) + 63 - lane];
            const int    bi = si[(lb << 6) + 63 - lane];
            if (BETTER(av, ai, bv, bi)) { cv = av; ci = ai; }
            else                        { cv = bv; ci = bi; }
            // bitonic merge of the (bitonic) top-64, best-first
#pragma unroll
            for (int j = 32; j > 0; j >>= 1) {
                const double pv = __shfl_xor(cv, j);
                const int    pi = __shfl_xor(ci, j);
                const bool lower = (lane & j) == 0;
                const bool ib = BETTER(cv, ci, pv, pi);
                const bool keep = lower ? ib : !ib;
                if (!keep) { cv = pv; ci = pi; }
            }
        }
        __syncthreads();                    // all reads of this round done
        if (active) {
            sk[(w << 6) + lane] = cv;
            si[(w << 6) + lane] = ci;
        }
        __syncthreads();                    // writes visible for next round
    }
#undef BETTER

    if (tid < 64) {
        tkidx[t * 64 + tid] = si[tid];
        tkval[t * 64 + tid] = tanhf((float)sk[tid]);
    }
}

// ---------------------------------------------------------------------------
// K_B qchain v6 (R20/R21-proven verbatim): 64 blocks x 256, 2 barriers/step.
// ---------------------------------------------------------------------------
__global__ __launch_bounds__(256) void qchain_kernel(
    const float* __restrict__ Q0,
    const float* __restrict__ Uu, const float* __restrict__ Ur,
    const float* __restrict__ Uh,
    const float* __restrict__ Wu, const float* __restrict__ Wr,
    const float* __restrict__ Wh,
    const float* __restrict__ bu, const float* __restrict__ br,
    const float* __restrict__ bh,
    const int* __restrict__ tkidx, const float* __restrict__ tkval,
    const float* __restrict__ X, unsigned short* __restrict__ Qtr)
{
    const int j = blockIdx.x, tid = threadIdx.x;
    const int w = tid >> 6, l = tid & 63;
    const int i = (w << 4) + (l & 15);
    const int fq = l >> 4, fb = fq << 4;

    __shared__ __align__(16) float zsh[TT][64];
    __shared__ __align__(16) float wzl[3 * TT * 64];
    __shared__ __align__(16) float qd[2][64];
    __shared__ __align__(16) float rr[64];

    {
        const int tt = tid >> 3, p8 = (tid & 7) << 3;
        const int idxt = tkidx[tt * 64 + j];
        const float th = tkval[tt * 64 + j];
        const float* xr = X + ((size_t)tt * NN + idxt) * FF + p8;
        float4 v0 = *(const float4*)(xr);
        float4 v1 = *(const float4*)(xr + 4);
        zsh[tt][p8]     = v0.x * th; zsh[tt][p8 + 1] = v0.y * th;
        zsh[tt][p8 + 2] = v0.z * th; zsh[tt][p8 + 3] = v0.w * th;
        zsh[tt][p8 + 4] = v1.x * th; zsh[tt][p8 + 5] = v1.y * th;
        zsh[tt][p8 + 6] = v1.z * th; zsh[tt][p8 + 7] = v1.w * th;
    }

    float uu[16], ur[16], uh[16], wu[16], wr[16], wh[16];
#pragma unroll
    for (int e = 0; e < 16; e += 4) {
        float4 a = *(const float4*)(Uu + i * 64 + fb + e);
        uu[e] = a.x; uu[e+1] = a.y; uu[e+2] = a.z; uu[e+3] = a.w;
        float4 c = *(const float4*)(Ur + i * 64 + fb + e);
        ur[e] = c.x; ur[e+1] = c.y; ur[e+2] = c.z; ur[e+3] = c.w;
        float4 d = *(const float4*)(Uh + i * 64 + fb + e);
        uh[e] = d.x; uh[e+1] = d.y; uh[e+2] = d.z; uh[e+3] = d.w;
        float4 p = *(const float4*)(Wu + i * 64 + fb + e);
        wu[e] = p.x; wu[e+1] = p.y; wu[e+2] = p.z; wu[e+3] = p.w;
        float4 s = *(const float4*)(Wr + i * 64 + fb + e);
        wr[e] = s.x; wr[e+1] = s.y; wr[e+2] = s.z; wr[e+3] = s.w;
        float4 g = *(const float4*)(Wh + i * 64 + fb + e);
        wh[e] = g.x; wh[e+1] = g.y; wh[e+2] = g.z; wh[e+3] = g.w;
    }
    const float bui = bu[i * 64 + j];
    const float bri = br[i * 64 + j];
    const float bhi = bh[i * 64 + j];
    if (tid < 64) qd[0][tid] = Q0[tid * 64 + j];
    __syncthreads();

    for (int t = 0; t < TT; ++t) {
        float z16[16];
#pragma unroll
        for (int e = 0; e < 16; e += 4) {
            f32x4 z = *(const f32x4*)(&zsh[t][fb + e]);
            z16[e] = z[0]; z16[e+1] = z[1]; z16[e+2] = z[2]; z16[e+3] = z[3];
        }
        float pu = 0.f, pr = 0.f, ph = 0.f;
#pragma unroll
        for (int e = 0; e < 16; ++e) {
            pu += wu[e] * z16[e];
            pr += wr[e] * z16[e];
            ph += wh[e] * z16[e];
        }
        pu += __shfl_xor(pu, 16); pu += __shfl_xor(pu, 32);
        pr += __shfl_xor(pr, 16); pr += __shfl_xor(pr, 32);
        ph += __shfl_xor(ph, 16); ph += __shfl_xor(ph, 32);
        if (fq == 0) {
            wzl[(0 * TT + t) * 64 + i] = pu;
            wzl[(1 * TT + t) * 64 + i] = pr;
            wzl[(2 * TT + t) * 64 + i] = ph;
        }
    }
    __syncthreads();

    int cur = 0;
    for (int t = 0; t < TT; ++t) {
        float q16[16];
#pragma unroll
        for (int e = 0; e < 16; e += 4) {
            f32x4 v = *(const f32x4*)(&qd[cur][fb + e]);
            q16[e] = v[0]; q16[e+1] = v[1]; q16[e+2] = v[2]; q16[e+3] = v[3];
        }
        float su = 0.f, sr = 0.f;
#pragma unroll
        for (int e = 0; e < 16; ++e) { su += uu[e] * q16[e]; sr += ur[e] * q16[e]; }
        su += __shfl_xor(su, 16); su += __shfl_xor(su, 32);
        sr += __shfl_xor(sr, 16); sr += __shfl_xor(sr, 32);
        const float u_ = 1.f / (1.f + expf(-(su + wzl[(0 * TT + t) * 64 + i] + bui)));
        const float r_ = 1.f / (1.f + expf(-(sr + wzl[(1 * TT + t) * 64 + i] + bri)));
        if (fq == 0) rr[i] = r_;
        __syncthreads();                       // B1: rr ready
        float sh = 0.f;
#pragma unroll
        for (int e = 0; e < 16; e += 4) {
            f32x4 v = *(const f32x4*)(&rr[fb + e]);
            sh += uh[e]   * (v[0] * q16[e]);
            sh += uh[e+1] * (v[1] * q16[e+1]);
            sh += uh[e+2] * (v[2] * q16[e+2]);
            sh += uh[e+3] * (v[3] * q16[e+3]);
        }
        sh += __shfl_xor(sh, 16); sh += __shfl_xor(sh, 32);
        float hv = sh + wzl[(2 * TT + t) * 64 + i] + bhi;
        hv = hv > 0.f ? hv : 0.f;
        const float qi = qd[cur][i];
        const float qn = (1.f - u_) * qi + u_ * hv;
        if (fq == 0) {
            qd[cur ^ 1][i] = qn;
            Qtr[(size_t)t * 4096 + j * 64 + i] = f2bf(qn);
        }
        __syncthreads();                       // B2: q[nxt] ready + rr WAR
        cur ^= 1;
    }
}

// ---------------------------------------------------------------------------
// K_C y-MFMA (R17-proven verbatim): Ytr[t][j][n] = bf16(Qtr[t][j].Xbf[t][n])
// ---------------------------------------------------------------------------
__global__ __launch_bounds__(256) void ymfma_kernel(
    const unsigned short* __restrict__ Xbf, const unsigned short* __restrict__ Qtr,
    unsigned short* __restrict__ Ytr)
{
    __shared__ __align__(16) unsigned char Qb[8192];   // bf16 [64 j][128B]
    const int t = blockIdx.y, tid = threadIdx.x;
    const int n0 = blockIdx.x * 256;
    const int lane = tid & 63, w = tid >> 6;
    const int lr = lane & 15, lq = lane >> 4;

    const unsigned short* Qp = Qtr + (size_t)t * 4096;
#pragma unroll
    for (int q2 = 0; q2 < 2; ++q2) {
        const int j = (w << 4) + (q2 << 3) + (lane >> 3);
        const unsigned short* g = Qp + (size_t)j * 64 + (((lane & 7) ^ (j & 7)) << 3);
        __builtin_amdgcn_global_load_lds(
            (const __attribute__((address_space(1))) void*)g,
            (__attribute__((address_space(3))) void*)
                (&Qb[((w << 4) + (q2 << 3)) << 7]), 16, 0, 0);
    }
    __syncthreads();

    f32x4 acc[4][4];
#pragma unroll
    for (int jt = 0; jt < 4; ++jt)
#pragma unroll
        for (int nt = 0; nt < 4; ++nt) acc[jt][nt] = (f32x4){0.f, 0.f, 0.f, 0.f};

#pragma unroll
    for (int ks = 0; ks < 2; ++ks) {
        bf16x8 af[4], bf[4];
#pragma unroll
        for (int jt = 0; jt < 4; ++jt) {
            const int j = (jt << 4) + lr;
            const int x = ((ks << 2) + lq) ^ (j & 7);
            af[jt] = *(const bf16x8*)(&Qb[(j << 7) + (x << 4)]);
        }
#pragma unroll
        for (int nt = 0; nt < 4; ++nt) {
            const int n = n0 + (w << 6) + (nt << 4) + lr;
            bf[nt] = __builtin_bit_cast(bf16x8,
                *(const uint4*)(Xbf + ((size_t)t * NN + n) * FF + (ks << 5) + (lq << 3)));
        }
#pragma unroll
        for (int jt = 0; jt < 4; ++jt)
#pragma unroll
            for (int nt = 0; nt < 4; ++nt)
                acc[jt][nt] = __builtin_amdgcn_mfma_f32_16x16x32_bf16(
                    af[jt], bf[nt], acc[jt][nt], 0, 0, 0);
    }

#pragma unroll
    for (int jt = 0; jt < 4; ++jt)
#pragma unroll
        for (int nt = 0; nt < 4; ++nt) {
            const int nn = n0 + (w << 6) + (nt << 4) + lr;
#pragma unroll
            for (int rg = 0; rg < 4; ++rg) {
                const int j = (jt << 4) + (lq << 2) + rg;
                Ytr[(size_t)t * FF * NN + (size_t)j * NN + nn] = f2bf(acc[jt][nt][rg]);
            }
        }
}

// ---------------------------------------------------------------------------
// K_D: out[t] = relu(A[t] @ Y[t]).  R10 gemm (measured 112us @ 4.6 TB/s).
// ---------------------------------------------------------------------------
__global__ __launch_bounds__(256, 4) void gemm_kernel(
    const float* __restrict__ A, const unsigned short* __restrict__ Ytr,
    float* __restrict__ out)
{
    __shared__ __align__(16) unsigned char Abuf[16384];  // f32 [64 r][256B]
    __shared__ __align__(16) unsigned char Bbuf[8192];   // bf16 [64 j][128B]
    const int tid = threadIdx.x;
    const int bid = blockIdx.x;
    const int xcd = bid & 7, li = bid >> 3;          // 8 XCDs x 128 blocks
    const int t = (xcd << 2) + (li >> 5);            // 4 timesteps per XCD
    const int m0 = (li & 31) * 64;
    const int lane = tid & 63, w = tid >> 6;
    const int lr = lane & 15, lq = lane >> 4;

    const float* Ap = A + (size_t)t * NN * NN + (size_t)m0 * NN;
    const unsigned short* Yp = Ytr + (size_t)t * FF * NN;

    f32x4 acc[4];
#pragma unroll
    for (int nt = 0; nt < 4; ++nt) acc[nt] = (f32x4){0.f, 0.f, 0.f, 0.f};

    for (int kt = 0; kt < 32; ++kt) {
        const int kk = kt << 6;
#pragma unroll
        for (int q = 0; q < 4; ++q) {
            const int row = (w << 4) + (q << 2) + lq;
            const float* g = Ap + (size_t)row * NN + kk + ((lr ^ (row & 7)) << 2);
            __builtin_amdgcn_global_load_lds(
                (const __attribute__((address_space(1))) void*)g,
                (__attribute__((address_space(3))) void*)
                    (&Abuf[((w << 4) + (q << 2)) << 8]), 16, 0, 0);
        }
#pragma unroll
        for (int q = 0; q < 2; ++q) {
            const int j = (w << 4) + (q << 3) + (lane >> 3);
            const unsigned short* g = Yp + (size_t)j * NN + kk
                                    + (((lane & 7) ^ (j & 7)) << 3);
            __builtin_amdgcn_global_load_lds(
                (const __attribute__((address_space(1))) void*)g,
                (__attribute__((address_space(3))) void*)
                    (&Bbuf[((w << 4) + (q << 3)) << 7]), 16, 0, 0);
        }
        __syncthreads();
#pragma unroll
        for (int ks = 0; ks < 2; ++ks) {
            const int r = (w << 4) + lr;
            const int c0 = ((ks << 3) + (lq << 1)) ^ (lr & 7);
            const int c1 = ((ks << 3) + (lq << 1) + 1) ^ (lr & 7);
            const f32x4 a0 = *(const f32x4*)(&Abuf[(r << 8) + (c0 << 4)]);
            const f32x4 a1 = *(const f32x4*)(&Abuf[(r << 8) + (c1 << 4)]);
            bf16x8 af;
            af[0] = (__bf16)a0[0]; af[1] = (__bf16)a0[1];
            af[2] = (__bf16)a0[2]; af[3] = (__bf16)a0[3];
            af[4] = (__bf16)a1[0]; af[5] = (__bf16)a1[1];
            af[6] = (__bf16)a1[2]; af[7] = (__bf16)a1[3];
#pragma unroll
            for (int nt = 0; nt < 4; ++nt) {
                const int j = (nt << 4) + lr;
                const int x = ((ks << 2) + lq) ^ (j & 7);
                const bf16x8 bf = *(const bf16x8*)(&Bbuf[(j << 7) + (x << 4)]);
                acc[nt] = __builtin_amdgcn_mfma_f32_16x16x32_bf16(
                    af, bf, acc[nt], 0, 0, 0);
            }
        }
        __syncthreads();
    }

#pragma unroll
    for (int nt = 0; nt < 4; ++nt) {
        const int row0 = m0 + (w << 4) + (lq << 2);
        const int col = (nt << 4) + lr;
#pragma unroll
        for (int rg = 0; rg < 4; ++rg) {
            const float v = acc[nt][rg];
            out[((size_t)t * NN + (row0 + rg)) * FF + col] = v > 0.f ? v : 0.f;
        }
    }
}

// ---------------------------------------------------------------------------
extern "C" void kernel_launch(void* const* d_in, const int* in_sizes, int n_in,
                              void* d_out, int out_size, void* d_ws, size_t ws_size,
                              hipStream_t stream) {
    const float* A      = (const float*)d_in[0];
    const float* X      = (const float*)d_in[1];
    const float* mask   = (const float*)d_in[2];
    const float* Q0     = (const float*)d_in[3];
    const float* scorer = (const float*)d_in[4];
    const float* Wu     = (const float*)d_in[5];
    const float* Uu     = (const float*)d_in[6];
    const float* bu     = (const float*)d_in[7];
    const float* Wr     = (const float*)d_in[8];
    const float* Ur     = (const float*)d_in[9];
    const float* br     = (const float*)d_in[10];
    const float* Wh     = (const float*)d_in[11];
    const float* Uh     = (const float*)d_in[12];
    const float* bh     = (const float*)d_in[13];
    float* out = (float*)d_out;

    float* ws = (float*)d_ws;
    double* scores        = (double*)ws;                          // [32][2048] fp64
    int*    tkidx         = (int*)(ws + 131072);                  // [32][64]
    float*  tkval         = ws + 133120;                          // [32][64]
    unsigned short* Qtr   = (unsigned short*)(ws + 135168);       // [32][64][64] bf16
    unsigned short* Xbf   = (unsigned short*)(ws + 200704);       // [32][2048][64] bf16
    unsigned short* Ytr   = (unsigned short*)(ws + 2297856);      // [32][64][2048] bf16

    score_kernel<<<dim3(8, TT), 256, 0, stream>>>(X, mask, scorer, scores, Xbf);
    select_kernel<<<TT, 1024, 0, stream>>>(scores, tkidx, tkval);
    qchain_kernel<<<FF, 256, 0, stream>>>(Q0, Uu, Ur, Uh, Wu, Wr, Wh,
                                          bu, br, bh, tkidx, tkval, X, Qtr);
    ymfma_kernel<<<dim3(8, TT), 256, 0, stream>>>(Xbf, Qtr, Ytr);
    gemm_kernel<<<1024, 256, 0, stream>>>(A, Ytr, out);
}